// Round 4
// baseline (736.304 us; speedup 1.0000x reference)
//
#include <hip/hip_runtime.h>
#include <stdint.h>
#include <stddef.h>

// Problem constants
#define S_LEN 128
#define B_SZ  64
#define V_SZ  32000
#define EH    512
#define EO    512
#define H_SZ  1024
#define O_SZ  1024
#define G3    3072   // 3*H

typedef __attribute__((ext_vector_type(8))) short short8;
typedef __attribute__((ext_vector_type(4))) float floatx4;
typedef __attribute__((ext_vector_type(8))) unsigned short ushortx8;
typedef __attribute__((ext_vector_type(4))) unsigned uintx4;

__device__ __forceinline__ unsigned short f2bf(float f) {
  unsigned u = __builtin_bit_cast(unsigned, f);
  u += 0x7FFFu + ((u >> 16) & 1u);   // round-to-nearest-even
  return (unsigned short)(u >> 16);
}
__device__ __forceinline__ float bf2f(unsigned short h) {
  unsigned u = ((unsigned)h) << 16;
  return __builtin_bit_cast(float, u);
}

__device__ __forceinline__ void gld_lds16(const void* g, void* l) {
  __builtin_amdgcn_global_load_lds((const __attribute__((address_space(1))) void*)g,
                                   (__attribute__((address_space(3))) void*)l, 16, 0, 0);
}

// ---------------------------------------------------------------- converts
// Fused fp32->bf16 convert of W2 / W_ih / W_out into ONE contiguous output
// region (W2b | Wihb | Woutb allocated back-to-back, all multiples of 256 B).
__global__ __launch_bounds__(256) void cvt3_bf16(const float* __restrict__ a,
                                                 const float* __restrict__ b,
                                                 const float* __restrict__ c,
                                                 unsigned short* __restrict__ out) {
  const int na4 = (EO * EH) / 4;        // 65536
  const int nb4 = (G3 * EO) / 4;        // 393216
  int i = blockIdx.x * 256 + threadIdx.x;   // grid sized exactly: 720896 total
  const float* src;
  int off;
  if (i < na4)            { src = a; off = i; }
  else if (i < na4 + nb4) { src = b; off = i - na4; }
  else                    { src = c; off = i - na4 - nb4; }
  float4 v = ((const float4*)src)[off];
  ushort4 o;
  o.x = f2bf(v.x); o.y = f2bf(v.y); o.z = f2bf(v.z); o.w = f2bf(v.w);
  ((ushort4*)out)[i] = o;
}

// ------------------------------------------------- W1 [EH][V] -> W1T bf16 [V][EH]
__global__ __launch_bounds__(256) void transpose_w1_bf16(const float* __restrict__ W1,
                                                         unsigned short* __restrict__ W1T) {
  __shared__ unsigned short tile[64][72];   // [v][e], padded
  int t = threadIdx.x;
  int v0 = blockIdx.x * 64;
  int e0 = blockIdx.y * 64;
  for (int i = 0; i < 4; ++i) {
    int e = (t >> 4) + i * 16;
    int v = (t & 15) * 4;
    float4 w = *(const float4*)&W1[(size_t)(e0 + e) * V_SZ + v0 + v];
    tile[v + 0][e] = f2bf(w.x);
    tile[v + 1][e] = f2bf(w.y);
    tile[v + 2][e] = f2bf(w.z);
    tile[v + 3][e] = f2bf(w.w);
  }
  __syncthreads();
  for (int i = 0; i < 2; ++i) {
    int v = (t >> 3) + i * 32;
    int e = (t & 7) * 8;
    ushortx8 o;
    for (int j = 0; j < 8; ++j) o[j] = tile[v][e + j];
    *(ushortx8*)&W1T[(size_t)(v0 + v) * EH + e0 + e] = o;
  }
}

// ------------------------------------------------- gather + b1 + threshold -> emb bf16
__global__ __launch_bounds__(256) void gather_emb(const int* __restrict__ ids,
                                                  const unsigned short* __restrict__ W1T,
                                                  const float* __restrict__ b1,
                                                  unsigned short* __restrict__ emb) {
  int t = threadIdx.x;
  int tok = blockIdx.x * 4 + (t >> 6);
  int lane = t & 63;
  int id = ids[tok];
  ushortx8 w = *(const ushortx8*)&W1T[(size_t)id * EH + lane * 8];
  float4 blo = *(const float4*)&b1[lane * 8];
  float4 bhi = *(const float4*)&b1[lane * 8 + 4];
  float bv[8] = {blo.x, blo.y, blo.z, blo.w, bhi.x, bhi.y, bhi.z, bhi.w};
  ushortx8 o;
  for (int j = 0; j < 8; ++j) {
    float x = bf2f(w[j]) + bv[j];
    x = (x > 1e-6f) ? x : 0.0f;
    o[j] = f2bf(x);
  }
  *(ushortx8*)&emb[(size_t)tok * EH + lane * 8] = o;
}

// ------------------------------------------------- MFMA GEMM, C = act(A @ B^T + bias)
// BK=64 + T2 XOR-swizzled LDS (16-B slots, slot ^= row&7); LDS dest of
// global_load_lds stays LINEAR, swizzle applied to the GLOBAL source slot.
template <int ACT, int OUT_BF16>
__global__ __launch_bounds__(256) void gemm_bt(const unsigned short* __restrict__ A,
                                               const unsigned short* __restrict__ B,
                                               const float* __restrict__ bias,
                                               void* __restrict__ Cout,
                                               int M, int N, int K) {
  __shared__ unsigned short lA[128 * 64];   // 16 KB, [row][slot^(row&7)] 16-B slots
  __shared__ unsigned short lB[128 * 64];   // 16 KB
  int t = threadIdx.x;
  int lane = t & 63;
  int wave = t >> 6;
  int bn = blockIdx.x, bm = blockIdx.y;
  int wm = (wave >> 1) * 64;
  int wn = (wave & 1) * 64;
  floatx4 acc[4][4] = {};

  int srow = t >> 3;                       // 0..31 within pass
  int sslot = (t & 7) ^ (srow & 7);        // logical (global) 16-B slot
  int scol = sslot * 8;                    // element offset within BK=64

  const unsigned short* aptr[4];
  const unsigned short* bptr[4];
#pragma unroll
  for (int p = 0; p < 4; ++p) {
    int gra = bm * 128 + p * 32 + srow;  if (gra >= M) gra = M - 1;
    aptr[p] = A + (size_t)gra * K + scol;
    bptr[p] = B + (size_t)(bn * 128 + p * 32 + srow) * K + scol;
  }

  for (int k0 = 0; k0 < K; k0 += 64) {
    __syncthreads();
#pragma unroll
    for (int p = 0; p < 4; ++p) {
      gld_lds16(aptr[p] + k0, &lA[p * 2048 + t * 8]);
      gld_lds16(bptr[p] + k0, &lB[p * 2048 + t * 8]);
    }
    __syncthreads();
#pragma unroll
    for (int kk = 0; kk < 2; ++kk) {
      short8 af[4], bfr[4];
#pragma unroll
      for (int i = 0; i < 4; ++i) {
        int row = wm + i * 16 + (lane & 15);
        int phys = (kk * 4 + (lane >> 4)) ^ (row & 7);
        af[i] = *(const short8*)&lA[row * 64 + phys * 8];
      }
#pragma unroll
      for (int j = 0; j < 4; ++j) {
        int row = wn + j * 16 + (lane & 15);
        int phys = (kk * 4 + (lane >> 4)) ^ (row & 7);
        bfr[j] = *(const short8*)&lB[row * 64 + phys * 8];
      }
#pragma unroll
      for (int i = 0; i < 4; ++i)
#pragma unroll
        for (int j = 0; j < 4; ++j)
          acc[i][j] = __builtin_amdgcn_mfma_f32_16x16x32_bf16(af[i], bfr[j], acc[i][j], 0, 0, 0);
    }
  }

  int rowq = (lane >> 4) * 4;
  for (int j = 0; j < 4; ++j) {
    int col = bn * 128 + wn + j * 16 + (lane & 15);
    float bv = bias[col];
    for (int i = 0; i < 4; ++i) {
      int row0 = bm * 128 + wm + i * 16 + rowq;
      for (int r = 0; r < 4; ++r) {
        int row = row0 + r;
        if (row < M) {
          float v = acc[i][j][r] + bv;
          if (ACT) v = (v > 1e-6f) ? v : 0.0f;
          if (OUT_BF16) ((unsigned short*)Cout)[(size_t)row * N + col] = f2bf(v);
          else          ((float*)Cout)[(size_t)row * N + col] = v;
        }
      }
    }
  }
}

// ------------------------------------------------- W_hh fp32 [3H][H] -> Wprep bf16 in
// MFMA-B-fragment order (see gru_persist).
__global__ __launch_bounds__(256) void prep_whh(const float* __restrict__ W_hh,
                                                unsigned short* __restrict__ Wprep) {
  int tid = blockIdx.x * 256 + threadIdx.x;   // 393216 total
  int lane = tid & 63;
  int c = tid >> 6;          // chunk 0..6143
  int cg = c / 96;
  int r  = c % 96;
  int g  = r >> 5;
  int t  = r & 31;
  int row = g * H_SZ + cg * 16 + (lane & 15);
  int k   = t * 32 + (lane >> 4) * 8;
  const float* src = &W_hh[(size_t)row * H_SZ + k];
  float4 v0 = *(const float4*)src;
  float4 v1 = *(const float4*)(src + 4);
  ushortx8 o;
  o[0] = f2bf(v0.x); o[1] = f2bf(v0.y); o[2] = f2bf(v0.z); o[3] = f2bf(v0.w);
  o[4] = f2bf(v1.x); o[5] = f2bf(v1.y); o[6] = f2bf(v1.z); o[7] = f2bf(v1.w);
  ((ushortx8*)Wprep)[tid] = o;
}

// ------------------------------------------------- persistent GRU recurrence
// 256 blocks x 256 threads, cooperative. Block (bg,cg): batches [bg*16,+16),
// h-cols [cg*16,+16), all 3 gates; wave w = K-quarter [w*256,+256).
// Round-0 skeleton (measured 2.93 us/step) with ONE change: the per-bg arrive
// counter is split 1 -> 8 (8 arrivals each, 128-B apart = distinct LLC lines)
// to cut same-address RMW serialization 64-way -> 8-way. Detect: lanes t<8 of
// wave 0 each sleepy-poll one counter (per-lane exec exit). Everything else
// byte-identical to the proven round-0/3 kernel.
__global__ __launch_bounds__(256) void gru_persist(const unsigned short* __restrict__ hprep0,
                                                   unsigned short* __restrict__ hprep1,
                                                   unsigned short* __restrict__ hbfinal,
                                                   const unsigned short* __restrict__ Wprep,
                                                   const float* __restrict__ b_hh,
                                                   const unsigned short* __restrict__ xW,
                                                   unsigned* __restrict__ bar) {
  __shared__ unsigned short lB[96 * 512];   // 98304 B : W_hh slice, fragment order
  __shared__ float lgh[3][4][256];          // 12288 B : per-wave K-partials
  __shared__ float lhf[256];                //  1024 B : fp32 master h slice
  int t = threadIdx.x;
  int lane = t & 63;
  int w = t >> 6;
  int bg = blockIdx.x >> 6;    // 0..3
  int cg = blockIdx.x & 63;    // 0..63

  // stage W_hh slice once (identity copy, 98 KB)
  const unsigned short* wsrc = Wprep + (size_t)cg * 96 * 512;
  for (int i = 0; i < 24; ++i) {
    int c = w * 24 + i;
    gld_lds16(wsrc + (size_t)c * 512 + lane * 8, &lB[c * 512 + lane * 8]);
  }
  lhf[t] = 0.0f;

  // per-thread update-element constants
  int b_loc = t >> 4;
  int j_loc = t & 15;
  int jcol = cg * 16 + j_loc;          // h column
  int bglob = bg * 16 + b_loc;         // batch
  float bhr = b_hh[jcol];
  float bhz = b_hh[H_SZ + jcol];
  float bhn = b_hh[2 * H_SZ + jcol];
  // scatter-store position for h_new (A-fragment layout); lane pairs (jj even/odd)
  // pack 2 bf16 into one dword store.
  int tt2 = jcol >> 5;
  int q   = (jcol >> 3) & 3;
  int jj  = jcol & 7;
  int Ls  = b_loc | (q << 4);
  size_t hw_off32 = ((((size_t)(bg * 32 + tt2) * 64 + Ls) * 8) + (jj & ~1)) >> 1;

  const unsigned short* hbufs[2] = {hprep0, hprep1};
  // split arrive counters: bar[(bg*8 + g) * 32], g = cg>>3, 128-B spacing
  unsigned* arrp  = bar + (size_t)(bg * 8 + (cg >> 3)) * 32;
  unsigned* pollp = bar + (size_t)(bg * 8 + (t & 7)) * 32;   // lanes t<8 use this
  __syncthreads();   // drains staging vmcnt

  for (int s = 0; s < S_LEN; ++s) {
    const unsigned short* hr = hbufs[s & 1];
    unsigned* hw32 = (unsigned*)hbufs[(s + 1) & 1];

    // A-fragments for my K-quarter: 8 x 16B coherent (sc1) loads, pipelined,
    // one tied waitcnt. Bypasses stale L1/L2 without any cache-wide inv.
    uintx4 av[8];
#pragma unroll
    for (int i = 0; i < 8; ++i) {
      int tt = w * 8 + i;
      const void* ap = hr + ((size_t)(bg * 32 + tt) * 64 + lane) * 8;
      asm volatile("global_load_dwordx4 %0, %1, off sc1" : "=v"(av[i]) : "v"(ap));
    }
    // xw loads (plain cached; produced before kernel launch)
    const unsigned short* xs = xW + (size_t)s * B_SZ * G3 + (size_t)bglob * G3;
    float xr = bf2f(xs[jcol]);
    float xz = bf2f(xs[H_SZ + jcol]);
    float xn = bf2f(xs[2 * H_SZ + jcol]);
    asm volatile("s_waitcnt vmcnt(0)"
                 : "+v"(av[0]), "+v"(av[1]), "+v"(av[2]), "+v"(av[3]),
                   "+v"(av[4]), "+v"(av[5]), "+v"(av[6]), "+v"(av[7])
                 :: "memory");

    floatx4 acc[3] = {};
#pragma unroll
    for (int i = 0; i < 8; ++i) {
      int tt = w * 8 + i;
      short8 a = __builtin_bit_cast(short8, av[i]);
#pragma unroll
      for (int g = 0; g < 3; ++g) {
        short8 bfr = *(const short8*)&lB[((g * 32 + tt) * 64 + lane) * 8];
        acc[g] = __builtin_amdgcn_mfma_f32_16x16x32_bf16(a, bfr, acc[g], 0, 0, 0);
      }
    }
#pragma unroll
    for (int g = 0; g < 3; ++g)
#pragma unroll
      for (int r = 0; r < 4; ++r)
        lgh[g][w][((lane >> 4) * 4 + r) * 16 + (lane & 15)] = acc[g][r];
    __syncthreads();

    // gate update for my element (sum 4 K-partials)
    float ghr = lgh[0][0][t] + lgh[0][1][t] + lgh[0][2][t] + lgh[0][3][t] + bhr;
    float ghz = lgh[1][0][t] + lgh[1][1][t] + lgh[1][2][t] + lgh[1][3][t] + bhz;
    float ghn = lgh[2][0][t] + lgh[2][1][t] + lgh[2][2][t] + lgh[2][3][t] + bhn;
    float rr = 1.0f / (1.0f + __expf(-(xr + ghr)));
    float zz = 1.0f / (1.0f + __expf(-(xz + ghz)));
    float nn = tanhf(xn + rr * ghn);
    float ho = lhf[t];
    float hnew = (1.0f - zz) * nn + zz * ho;
    lhf[t] = hnew;

    unsigned hb = (unsigned)f2bf(hnew);
    unsigned other = (unsigned)__shfl_xor((int)hb, 1);
    if ((jj & 1) == 0) {
      unsigned packed = hb | (other << 16);   // (jj, jj+1)
      __hip_atomic_store(hw32 + hw_off32, packed,
                         __ATOMIC_RELAXED, __HIP_MEMORY_SCOPE_AGENT);
    }
    if (s == S_LEN - 1) hbfinal[(size_t)bglob * H_SZ + jcol] = (unsigned short)hb;

    if (s < S_LEN - 1) {
      __syncthreads();   // waitcnt vmcnt(0) + barrier: all block h-stores at L3
      if (t < 8) {
        if (t == 0)
          __hip_atomic_fetch_add(arrp, 1u, __ATOMIC_RELAXED, __HIP_MEMORY_SCOPE_AGENT);
        unsigned target = 8u * (unsigned)(s + 1);
        while (__hip_atomic_load(pollp, __ATOMIC_RELAXED, __HIP_MEMORY_SCOPE_AGENT) < target)
          __builtin_amdgcn_s_sleep(2);
      }
      __syncthreads();
    }
  }
}

// ----------------------------------------------------------------- launch
extern "C" void kernel_launch(void* const* d_in, const int* in_sizes, int n_in,
                              void* d_out, int out_size, void* d_ws, size_t ws_size,
                              hipStream_t stream) {
  const int*   ids   = (const int*)d_in[0];
  const float* W1    = (const float*)d_in[1];
  const float* b1    = (const float*)d_in[2];
  const float* W2    = (const float*)d_in[3];
  const float* b2    = (const float*)d_in[4];
  const float* W_ih  = (const float*)d_in[5];
  const float* b_ih  = (const float*)d_in[6];
  const float* W_hh  = (const float*)d_in[7];
  const float* b_hh  = (const float*)d_in[8];
  const float* W_out = (const float*)d_in[9];
  const float* b_out = (const float*)d_in[10];
  float* out = (float*)d_out;

  uint8_t* wsp = (uint8_t*)d_ws;
  auto alloc = [&](size_t bytes) {
    uint8_t* p = wsp;
    wsp += (bytes + 255) & ~(size_t)255;
    return p;
  };
  unsigned short* W1T   = (unsigned short*)alloc((size_t)V_SZ * EH * 2);
  // NOTE: W2b/Wihb/Woutb must stay contiguous & in this order (cvt3_bf16 fuses
  // all three converts into one launch over the concatenated region).
  unsigned short* W2b   = (unsigned short*)alloc((size_t)EO * EH * 2);
  unsigned short* Wihb  = (unsigned short*)alloc((size_t)G3 * EO * 2);
  unsigned short* Woutb = (unsigned short*)alloc((size_t)O_SZ * H_SZ * 2);
  unsigned short* Wprep = (unsigned short*)alloc((size_t)G3 * H_SZ * 2);
  unsigned short* emb   = (unsigned short*)alloc((size_t)S_LEN * B_SZ * EH * 2);
  unsigned short* x     = (unsigned short*)alloc((size_t)S_LEN * B_SZ * EO * 2);
  unsigned short* xW    = (unsigned short*)alloc((size_t)S_LEN * B_SZ * G3 * 2);
  unsigned short* hprep0 = (unsigned short*)alloc((size_t)B_SZ * H_SZ * 2);
  unsigned short* hprep1 = (unsigned short*)alloc((size_t)B_SZ * H_SZ * 2);
  unsigned short* hbfinal = (unsigned short*)alloc((size_t)B_SZ * H_SZ * 2);
  unsigned*       bar     = (unsigned*)alloc(4096);   // 32 counters, 128-B spaced

  // fused weight converts (fp32 -> bf16): W2 | W_ih | W_out -> one launch
  cvt3_bf16<<<dim3(2816), 256, 0, stream>>>(W2, W_ih, W_out, W2b);

  // W_hh -> MFMA-fragment-ordered bf16
  prep_whh<<<dim3(1536), 256, 0, stream>>>(W_hh, Wprep);

  // zero h0 (fragment-layout buffer read at s=0) and the arrive counters
  hipMemsetAsync(hprep0, 0, (size_t)B_SZ * H_SZ * 2, stream);
  hipMemsetAsync(bar, 0, 4096, stream);

  // W1 transpose -> bf16
  transpose_w1_bf16<<<dim3(V_SZ / 64, EH / 64), 256, 0, stream>>>(W1, W1T);

  // embedding gather + b1 + threshold
  gather_emb<<<dim3(S_LEN * B_SZ / 4), 256, 0, stream>>>(ids, W1T, b1, emb);

  // x = thresh(emb @ W2^T + b2)
  gemm_bt<1, 1><<<dim3(EO / 128, S_LEN * B_SZ / 128), 256, 0, stream>>>(
      emb, W2b, b2, x, S_LEN * B_SZ, EO, EH);

  // xW = x @ W_ih^T + b_ih
  gemm_bt<0, 1><<<dim3(G3 / 128, S_LEN * B_SZ / 128), 256, 0, stream>>>(
      x, Wihb, b_ih, xW, S_LEN * B_SZ, G3, EO);

  // persistent GRU recurrence (cooperative: all 256 blocks co-resident)
  {
    void* args[] = {(void*)&hprep0, (void*)&hprep1, (void*)&hbfinal,
                    (void*)&Wprep, (void*)&b_hh, (void*)&xW, (void*)&bar};
    hipLaunchCooperativeKernel((const void*)gru_persist, dim3(256), dim3(256),
                               args, 0, stream);
  }

  // out = h @ W_out^T + b_out
  gemm_bt<0, 0><<<dim3(O_SZ / 128, 1), 256, 0, stream>>>(
      hbfinal, Woutb, b_out, out, B_SZ, O_SZ, H_SZ);
}

// Round 5
// 699.034 us; speedup vs baseline: 1.0533x; 1.0533x over previous
//
#include <hip/hip_runtime.h>
#include <stdint.h>
#include <stddef.h>

// Problem constants
#define S_LEN 128
#define B_SZ  64
#define V_SZ  32000
#define EH    512
#define EO    512
#define H_SZ  1024
#define O_SZ  1024
#define G3    3072   // 3*H

typedef __attribute__((ext_vector_type(8))) short short8;
typedef __attribute__((ext_vector_type(4))) float floatx4;
typedef __attribute__((ext_vector_type(8))) unsigned short ushortx8;
typedef __attribute__((ext_vector_type(4))) unsigned uintx4;

__device__ __forceinline__ unsigned short f2bf(float f) {
  unsigned u = __builtin_bit_cast(unsigned, f);
  u += 0x7FFFu + ((u >> 16) & 1u);   // round-to-nearest-even
  return (unsigned short)(u >> 16);
}
__device__ __forceinline__ float bf2f(unsigned short h) {
  unsigned u = ((unsigned)h) << 16;
  return __builtin_bit_cast(float, u);
}

__device__ __forceinline__ void gld_lds16(const void* g, void* l) {
  __builtin_amdgcn_global_load_lds((const __attribute__((address_space(1))) void*)g,
                                   (__attribute__((address_space(3))) void*)l, 16, 0, 0);
}

// ---------------------------------------------------------------- converts
// Fused fp32->bf16 convert of W2 | W_out into ONE contiguous output region
// (W2b | Woutb allocated back-to-back, both multiples of 256 B).
__global__ __launch_bounds__(256) void cvt2_bf16(const float* __restrict__ a,
                                                 const float* __restrict__ b,
                                                 unsigned short* __restrict__ out) {
  const int na4 = (EO * EH) / 4;        // 65536
  int i = blockIdx.x * 256 + threadIdx.x;   // grid sized exactly: 327680 total
  const float* src;
  int off;
  if (i < na4) { src = a; off = i; }
  else         { src = b; off = i - na4; }
  float4 v = ((const float4*)src)[off];
  ushort4 o;
  o.x = f2bf(v.x); o.y = f2bf(v.y); o.z = f2bf(v.z); o.w = f2bf(v.w);
  ((ushort4*)out)[i] = o;
}

// ------------------------------------------------- W1 [EH][V] -> W1T bf16 [V][EH]
__global__ __launch_bounds__(256) void transpose_w1_bf16(const float* __restrict__ W1,
                                                         unsigned short* __restrict__ W1T) {
  __shared__ unsigned short tile[64][72];   // [v][e], padded
  int t = threadIdx.x;
  int v0 = blockIdx.x * 64;
  int e0 = blockIdx.y * 64;
  for (int i = 0; i < 4; ++i) {
    int e = (t >> 4) + i * 16;
    int v = (t & 15) * 4;
    float4 w = *(const float4*)&W1[(size_t)(e0 + e) * V_SZ + v0 + v];
    tile[v + 0][e] = f2bf(w.x);
    tile[v + 1][e] = f2bf(w.y);
    tile[v + 2][e] = f2bf(w.z);
    tile[v + 3][e] = f2bf(w.w);
  }
  __syncthreads();
  for (int i = 0; i < 2; ++i) {
    int v = (t >> 3) + i * 32;
    int e = (t & 7) * 8;
    ushortx8 o;
    for (int j = 0; j < 8; ++j) o[j] = tile[v][e + j];
    *(ushortx8*)&W1T[(size_t)(v0 + v) * EH + e0 + e] = o;
  }
}

// ------------------------------------------------- gather + b1 + threshold -> emb bf16
__global__ __launch_bounds__(256) void gather_emb(const int* __restrict__ ids,
                                                  const unsigned short* __restrict__ W1T,
                                                  const float* __restrict__ b1,
                                                  unsigned short* __restrict__ emb) {
  int t = threadIdx.x;
  int tok = blockIdx.x * 4 + (t >> 6);
  int lane = t & 63;
  int id = ids[tok];
  ushortx8 w = *(const ushortx8*)&W1T[(size_t)id * EH + lane * 8];
  float4 blo = *(const float4*)&b1[lane * 8];
  float4 bhi = *(const float4*)&b1[lane * 8 + 4];
  float bv[8] = {blo.x, blo.y, blo.z, blo.w, bhi.x, bhi.y, bhi.z, bhi.w};
  ushortx8 o;
  for (int j = 0; j < 8; ++j) {
    float x = bf2f(w[j]) + bv[j];
    x = (x > 1e-6f) ? x : 0.0f;
    o[j] = f2bf(x);
  }
  *(ushortx8*)&emb[(size_t)tok * EH + lane * 8] = o;
}

// ------------------------------------------------- MFMA GEMM, C = act(A @ B^T + bias)
// BK=64 + T2 XOR-swizzled LDS (16-B slots, slot ^= row&7); LDS dest of
// global_load_lds stays LINEAR, swizzle applied to the GLOBAL source slot.
template <int ACT, int OUT_BF16>
__global__ __launch_bounds__(256) void gemm_bt(const unsigned short* __restrict__ A,
                                               const unsigned short* __restrict__ B,
                                               const float* __restrict__ bias,
                                               void* __restrict__ Cout,
                                               int M, int N, int K) {
  __shared__ unsigned short lA[128 * 64];   // 16 KB, [row][slot^(row&7)] 16-B slots
  __shared__ unsigned short lB[128 * 64];   // 16 KB
  int t = threadIdx.x;
  int lane = t & 63;
  int wave = t >> 6;
  int bn = blockIdx.x, bm = blockIdx.y;
  int wm = (wave >> 1) * 64;
  int wn = (wave & 1) * 64;
  floatx4 acc[4][4] = {};

  int srow = t >> 3;                       // 0..31 within pass
  int sslot = (t & 7) ^ (srow & 7);        // logical (global) 16-B slot
  int scol = sslot * 8;                    // element offset within BK=64

  const unsigned short* aptr[4];
  const unsigned short* bptr[4];
#pragma unroll
  for (int p = 0; p < 4; ++p) {
    int gra = bm * 128 + p * 32 + srow;  if (gra >= M) gra = M - 1;
    aptr[p] = A + (size_t)gra * K + scol;
    bptr[p] = B + (size_t)(bn * 128 + p * 32 + srow) * K + scol;
  }

  for (int k0 = 0; k0 < K; k0 += 64) {
    __syncthreads();
#pragma unroll
    for (int p = 0; p < 4; ++p) {
      gld_lds16(aptr[p] + k0, &lA[p * 2048 + t * 8]);
      gld_lds16(bptr[p] + k0, &lB[p * 2048 + t * 8]);
    }
    __syncthreads();
#pragma unroll
    for (int kk = 0; kk < 2; ++kk) {
      short8 af[4], bfr[4];
#pragma unroll
      for (int i = 0; i < 4; ++i) {
        int row = wm + i * 16 + (lane & 15);
        int phys = (kk * 4 + (lane >> 4)) ^ (row & 7);
        af[i] = *(const short8*)&lA[row * 64 + phys * 8];
      }
#pragma unroll
      for (int j = 0; j < 4; ++j) {
        int row = wn + j * 16 + (lane & 15);
        int phys = (kk * 4 + (lane >> 4)) ^ (row & 7);
        bfr[j] = *(const short8*)&lB[row * 64 + phys * 8];
      }
#pragma unroll
      for (int i = 0; i < 4; ++i)
#pragma unroll
        for (int j = 0; j < 4; ++j)
          acc[i][j] = __builtin_amdgcn_mfma_f32_16x16x32_bf16(af[i], bfr[j], acc[i][j], 0, 0, 0);
    }
  }

  int rowq = (lane >> 4) * 4;
  for (int j = 0; j < 4; ++j) {
    int col = bn * 128 + wn + j * 16 + (lane & 15);
    float bv = bias[col];
    for (int i = 0; i < 4; ++i) {
      int row0 = bm * 128 + wm + i * 16 + rowq;
      for (int r = 0; r < 4; ++r) {
        int row = row0 + r;
        if (row < M) {
          float v = acc[i][j][r] + bv;
          if (ACT) v = (v > 1e-6f) ? v : 0.0f;
          if (OUT_BF16) ((unsigned short*)Cout)[(size_t)row * N + col] = f2bf(v);
          else          ((float*)Cout)[(size_t)row * N + col] = v;
        }
      }
    }
  }
}

// ------------------------------------------------- W_hh fp32 [3H][H] -> Wprep bf16 in
// MFMA-B-fragment order (see gru_persist).
__global__ __launch_bounds__(256) void prep_whh(const float* __restrict__ W_hh,
                                                unsigned short* __restrict__ Wprep) {
  int tid = blockIdx.x * 256 + threadIdx.x;   // 393216 total
  int lane = tid & 63;
  int c = tid >> 6;          // chunk 0..6143
  int cg = c / 96;
  int r  = c % 96;
  int g  = r >> 5;
  int t  = r & 31;
  int row = g * H_SZ + cg * 16 + (lane & 15);
  int k   = t * 32 + (lane >> 4) * 8;
  const float* src = &W_hh[(size_t)row * H_SZ + k];
  float4 v0 = *(const float4*)src;
  float4 v1 = *(const float4*)(src + 4);
  ushortx8 o;
  o[0] = f2bf(v0.x); o[1] = f2bf(v0.y); o[2] = f2bf(v0.z); o[3] = f2bf(v0.w);
  o[4] = f2bf(v1.x); o[5] = f2bf(v1.y); o[6] = f2bf(v1.z); o[7] = f2bf(v1.w);
  ((ushortx8*)Wprep)[tid] = o;
}

// ------------------------------------------------- W_ih fp32 [3H][EO] -> Wihp bf16 in
// MFMA-B-fragment order, per-cg slices of 48 chunks (3 gates x 16 K-chunks of 32).
__global__ __launch_bounds__(256) void prep_wih(const float* __restrict__ W_ih,
                                                unsigned short* __restrict__ Wihp) {
  int tid = blockIdx.x * 256 + threadIdx.x;   // 196608 total
  int lane = tid & 63;
  int c = tid >> 6;          // chunk 0..3071
  int cg = c / 48;
  int r  = c % 48;
  int g  = r >> 4;
  int kq = r & 15;
  int row = g * H_SZ + cg * 16 + (lane & 15);
  int k   = kq * 32 + (lane >> 4) * 8;
  const float* src = &W_ih[(size_t)row * EO + k];
  float4 v0 = *(const float4*)src;
  float4 v1 = *(const float4*)(src + 4);
  ushortx8 o;
  o[0] = f2bf(v0.x); o[1] = f2bf(v0.y); o[2] = f2bf(v0.z); o[3] = f2bf(v0.w);
  o[4] = f2bf(v1.x); o[5] = f2bf(v1.y); o[6] = f2bf(v1.z); o[7] = f2bf(v1.w);
  ((ushortx8*)Wihp)[tid] = o;
}

// ------------------------------------------------- persistent GRU recurrence
// 256 blocks x 256 threads, cooperative. Block (bg,cg): batches [bg*16,+16),
// h-cols [cg*16,+16), all 3 gates; wave w = K-quarter [w*256,+256).
// Barrier: EXACT round-0 form (measured 2.93 us/step): per-bg monotonic
// fetch_add counter + single-lane s_sleep(2) poll. Four alternative barrier
// schemes (rounds 1/2/4) all regressed -- do not touch.
//
// NEW (round-5): the xW = x @ W_ih^T GEMM is folded INTO the barrier wait
// window. Waves 1-3 (idle while wave 0 polls) each compute one gate's
// 16x16 xW tile for step s+1 (16 MFMA, K=512) from plain cached x loads
// (LLC-resident) and the per-block W_ih slice staged in LDS (48 KB,
// fragment order via prep_wih). Results go to lgx; all threads pick them up
// after the release barrier. Removes the 1536-block xW GEMM dispatch and
// 96 MB of xW write+read traffic; adds zero work to the critical path.
__global__ __launch_bounds__(256) void gru_persist(const unsigned short* __restrict__ hprep0,
                                                   unsigned short* __restrict__ hprep1,
                                                   unsigned short* __restrict__ hbfinal,
                                                   const unsigned short* __restrict__ Wprep,
                                                   const unsigned short* __restrict__ Wihp,
                                                   const float* __restrict__ b_hh,
                                                   const float* __restrict__ b_ih,
                                                   const unsigned short* __restrict__ x,
                                                   unsigned* __restrict__ bar) {
  __shared__ unsigned short lB[96 * 512];    // 98304 B : W_hh slice, fragment order
  __shared__ unsigned short lWih[48 * 512];  // 49152 B : W_ih slice, fragment order
  __shared__ float lgh[3][4][256];           // 12288 B : per-wave K-partials
  __shared__ float lgx[3][256];              //  3072 B : xW tile for next step
  // total 162816 B of 163840 B LDS
  int t = threadIdx.x;
  int lane = t & 63;
  int w = t >> 6;
  int bg = blockIdx.x >> 6;    // 0..3
  int cg = blockIdx.x & 63;    // 0..63

  // stage W_hh slice once (identity copy, 98 KB)
  const unsigned short* wsrc = Wprep + (size_t)cg * 96 * 512;
  for (int i = 0; i < 24; ++i) {
    int c = w * 24 + i;
    gld_lds16(wsrc + (size_t)c * 512 + lane * 8, &lB[c * 512 + lane * 8]);
  }
  // stage W_ih slice once (48 KB)
  const unsigned short* wxs = Wihp + (size_t)cg * 48 * 512;
  for (int i = 0; i < 12; ++i) {
    int c = w * 12 + i;
    gld_lds16(wxs + (size_t)c * 512 + lane * 8, &lWih[c * 512 + lane * 8]);
  }

  // per-thread update-element constants
  int b_loc = t >> 4;
  int j_loc = t & 15;
  int jcol = cg * 16 + j_loc;          // h column
  int bglob = bg * 16 + b_loc;         // batch
  float bhr = b_hh[jcol];
  float bhz = b_hh[H_SZ + jcol];
  float bhn = b_hh[2 * H_SZ + jcol];
  float bihr = b_ih[jcol];
  float bihz = b_ih[H_SZ + jcol];
  float bihn = b_ih[2 * H_SZ + jcol];
  // scatter-store position for h_new (A-fragment layout); lane pairs (jj even/odd)
  // pack 2 bf16 into one dword store.
  int tt2 = jcol >> 5;
  int q   = (jcol >> 3) & 3;
  int jj  = jcol & 7;
  int Ls  = b_loc | (q << 4);
  size_t hw_off32 = ((((size_t)(bg * 32 + tt2) * 64 + Ls) * 8) + (jj & ~1)) >> 1;

  const unsigned short* hbufs[2] = {hprep0, hprep1};
  unsigned* barp = bar + bg * 64;      // per-bg counter, 256 B apart
  float hmaster = 0.0f;                // fp32 master h for my (batch, col)

  // xW tile for step sn, computed by waves 1-3 (gate = w-1) in the wait window.
  // A-frag rows = batches (lane&15), k = kq*32 + (lane>>4)*8 from row-major x;
  // B-frag from lWih chunk (g*16+kq); C goes to lgx in the lgh-store layout.
  auto xw_compute = [&](int sn) {
    int g = w - 1;
    const unsigned short* xrow =
        x + ((size_t)(sn * B_SZ + bg * 16 + (lane & 15))) * EO + (lane >> 4) * 8;
    floatx4 accx = {};
#pragma unroll
    for (int kq = 0; kq < 16; ++kq) {
      uintx4 xv = *(const uintx4*)(xrow + kq * 32);
      short8 a = __builtin_bit_cast(short8, xv);
      short8 bfr = *(const short8*)&lWih[((g * 16 + kq) * 64 + lane) * 8];
      accx = __builtin_amdgcn_mfma_f32_16x16x32_bf16(a, bfr, accx, 0, 0, 0);
    }
#pragma unroll
    for (int r = 0; r < 4; ++r)
      lgx[g][((lane >> 4) * 4 + r) * 16 + (lane & 15)] = accx[r];
  };

  __syncthreads();   // drains staging vmcnt (lB + lWih ready)

  // prologue: xW for s=0
  if (w >= 1) xw_compute(0);
  __syncthreads();
  float xr = lgx[0][t] + bihr;
  float xz = lgx[1][t] + bihz;
  float xn = lgx[2][t] + bihn;

  for (int s = 0; s < S_LEN; ++s) {
    const unsigned short* hr = hbufs[s & 1];
    unsigned* hw32 = (unsigned*)hbufs[(s + 1) & 1];

    // A-fragments for my K-quarter: 8 x 16B coherent (sc1) loads, pipelined,
    // one tied waitcnt. Bypasses stale L1/L2 without any cache-wide inv.
    uintx4 av[8];
#pragma unroll
    for (int i = 0; i < 8; ++i) {
      int tt = w * 8 + i;
      const void* ap = hr + ((size_t)(bg * 32 + tt) * 64 + lane) * 8;
      asm volatile("global_load_dwordx4 %0, %1, off sc1" : "=v"(av[i]) : "v"(ap));
    }
    asm volatile("s_waitcnt vmcnt(0)"
                 : "+v"(av[0]), "+v"(av[1]), "+v"(av[2]), "+v"(av[3]),
                   "+v"(av[4]), "+v"(av[5]), "+v"(av[6]), "+v"(av[7])
                 :: "memory");

    floatx4 acc[3] = {};
#pragma unroll
    for (int i = 0; i < 8; ++i) {
      int tt = w * 8 + i;
      short8 a = __builtin_bit_cast(short8, av[i]);
#pragma unroll
      for (int g = 0; g < 3; ++g) {
        short8 bfr = *(const short8*)&lB[((g * 32 + tt) * 64 + lane) * 8];
        acc[g] = __builtin_amdgcn_mfma_f32_16x16x32_bf16(a, bfr, acc[g], 0, 0, 0);
      }
    }
#pragma unroll
    for (int g = 0; g < 3; ++g)
#pragma unroll
      for (int r = 0; r < 4; ++r)
        lgh[g][w][((lane >> 4) * 4 + r) * 16 + (lane & 15)] = acc[g][r];
    __syncthreads();

    // gate update for my element (sum 4 K-partials)
    float ghr = lgh[0][0][t] + lgh[0][1][t] + lgh[0][2][t] + lgh[0][3][t] + bhr;
    float ghz = lgh[1][0][t] + lgh[1][1][t] + lgh[1][2][t] + lgh[1][3][t] + bhz;
    float ghn = lgh[2][0][t] + lgh[2][1][t] + lgh[2][2][t] + lgh[2][3][t] + bhn;
    float rr = 1.0f / (1.0f + __expf(-(xr + ghr)));
    float zz = 1.0f / (1.0f + __expf(-(xz + ghz)));
    float nn = tanhf(xn + rr * ghn);
    float hnew = (1.0f - zz) * nn + zz * hmaster;
    hmaster = hnew;

    unsigned hb = (unsigned)f2bf(hnew);
    unsigned other = (unsigned)__shfl_xor((int)hb, 1);
    if ((jj & 1) == 0) {
      unsigned packed = hb | (other << 16);   // (jj, jj+1)
      __hip_atomic_store(hw32 + hw_off32, packed,
                         __ATOMIC_RELAXED, __HIP_MEMORY_SCOPE_AGENT);
    }
    if (s == S_LEN - 1) hbfinal[(size_t)bglob * H_SZ + jcol] = (unsigned short)hb;

    if (s < S_LEN - 1) {
      __syncthreads();   // waitcnt vmcnt(0) + barrier: all block h-stores at L3
      if (w == 0) {
        if (t == 0) {
          __hip_atomic_fetch_add(barp, 1u, __ATOMIC_RELAXED, __HIP_MEMORY_SCOPE_AGENT);
          unsigned target = 64u * (unsigned)(s + 1);
          while (__hip_atomic_load(barp, __ATOMIC_RELAXED, __HIP_MEMORY_SCOPE_AGENT) < target)
            __builtin_amdgcn_s_sleep(2);
        }
      } else {
        // hidden under the poll: next step's xW tile (one gate per wave)
        xw_compute(s + 1);
      }
      __syncthreads();   // release; also publishes lgx
      xr = lgx[0][t] + bihr;
      xz = lgx[1][t] + bihz;
      xn = lgx[2][t] + bihn;
    }
  }
}

// ----------------------------------------------------------------- launch
extern "C" void kernel_launch(void* const* d_in, const int* in_sizes, int n_in,
                              void* d_out, int out_size, void* d_ws, size_t ws_size,
                              hipStream_t stream) {
  const int*   ids   = (const int*)d_in[0];
  const float* W1    = (const float*)d_in[1];
  const float* b1    = (const float*)d_in[2];
  const float* W2    = (const float*)d_in[3];
  const float* b2    = (const float*)d_in[4];
  const float* W_ih  = (const float*)d_in[5];
  const float* b_ih  = (const float*)d_in[6];
  const float* W_hh  = (const float*)d_in[7];
  const float* b_hh  = (const float*)d_in[8];
  const float* W_out = (const float*)d_in[9];
  const float* b_out = (const float*)d_in[10];
  float* out = (float*)d_out;

  uint8_t* wsp = (uint8_t*)d_ws;
  auto alloc = [&](size_t bytes) {
    uint8_t* p = wsp;
    wsp += (bytes + 255) & ~(size_t)255;
    return p;
  };
  unsigned short* W1T   = (unsigned short*)alloc((size_t)V_SZ * EH * 2);
  // NOTE: W2b/Woutb must stay contiguous & in this order (cvt2_bf16 fuses
  // both converts into one launch over the concatenated region).
  unsigned short* W2b   = (unsigned short*)alloc((size_t)EO * EH * 2);
  unsigned short* Woutb = (unsigned short*)alloc((size_t)O_SZ * H_SZ * 2);
  unsigned short* Wprep = (unsigned short*)alloc((size_t)G3 * H_SZ * 2);
  unsigned short* Wihp  = (unsigned short*)alloc((size_t)G3 * EO * 2);
  unsigned short* emb   = (unsigned short*)alloc((size_t)S_LEN * B_SZ * EH * 2);
  unsigned short* x     = (unsigned short*)alloc((size_t)S_LEN * B_SZ * EO * 2);
  unsigned short* hprep0 = (unsigned short*)alloc((size_t)B_SZ * H_SZ * 2);
  unsigned short* hprep1 = (unsigned short*)alloc((size_t)B_SZ * H_SZ * 2);
  unsigned short* hbfinal = (unsigned short*)alloc((size_t)B_SZ * H_SZ * 2);
  unsigned*       bar     = (unsigned*)alloc(1024);

  // fused weight converts (fp32 -> bf16): W2 | W_out -> one launch
  cvt2_bf16<<<dim3(1280), 256, 0, stream>>>(W2, W_out, W2b);

  // W_hh / W_ih -> MFMA-fragment-ordered bf16
  prep_whh<<<dim3(1536), 256, 0, stream>>>(W_hh, Wprep);
  prep_wih<<<dim3(768), 256, 0, stream>>>(W_ih, Wihp);

  // zero h0 (fragment-layout buffer read at s=0) and the 4 barrier counters
  hipMemsetAsync(hprep0, 0, (size_t)B_SZ * H_SZ * 2, stream);
  hipMemsetAsync(bar, 0, 1024, stream);

  // W1 transpose -> bf16
  transpose_w1_bf16<<<dim3(V_SZ / 64, EH / 64), 256, 0, stream>>>(W1, W1T);

  // embedding gather + b1 + threshold
  gather_emb<<<dim3(S_LEN * B_SZ / 4), 256, 0, stream>>>(ids, W1T, b1, emb);

  // x = thresh(emb @ W2^T + b2)
  gemm_bt<1, 1><<<dim3(EO / 128, S_LEN * B_SZ / 128), 256, 0, stream>>>(
      emb, W2b, b2, x, S_LEN * B_SZ, EO, EH);

  // persistent GRU recurrence (cooperative: all 256 blocks co-resident)
  // xW GEMM folded inside (computed per-step in the barrier wait window).
  {
    void* args[] = {(void*)&hprep0, (void*)&hprep1, (void*)&hbfinal,
                    (void*)&Wprep, (void*)&Wihp, (void*)&b_hh, (void*)&b_ih,
                    (void*)&x, (void*)&bar};
    hipLaunchCooperativeKernel((const void*)gru_persist, dim3(256), dim3(256),
                               args, 0, stream);
  }

  // out = h @ W_out^T + b_out
  gemm_bt<0, 0><<<dim3(O_SZ / 128, 1), 256, 0, stream>>>(
      hbfinal, Woutb, b_out, out, B_SZ, O_SZ, H_SZ);
}

// Round 6
// 674.877 us; speedup vs baseline: 1.0910x; 1.0358x over previous
//
#include <hip/hip_runtime.h>
#include <stdint.h>
#include <stddef.h>

// Problem constants
#define S_LEN 128
#define B_SZ  64
#define V_SZ  32000
#define EH    512
#define EO    512
#define H_SZ  1024
#define O_SZ  1024
#define G3    3072   // 3*H

typedef __attribute__((ext_vector_type(8))) short short8;
typedef __attribute__((ext_vector_type(4))) float floatx4;
typedef __attribute__((ext_vector_type(8))) unsigned short ushortx8;
typedef __attribute__((ext_vector_type(4))) unsigned uintx4;

__device__ __forceinline__ unsigned short f2bf(float f) {
  unsigned u = __builtin_bit_cast(unsigned, f);
  u += 0x7FFFu + ((u >> 16) & 1u);   // round-to-nearest-even
  return (unsigned short)(u >> 16);
}
__device__ __forceinline__ float bf2f(unsigned short h) {
  unsigned u = ((unsigned)h) << 16;
  return __builtin_bit_cast(float, u);
}

__device__ __forceinline__ void gld_lds16(const void* g, void* l) {
  __builtin_amdgcn_global_load_lds((const __attribute__((address_space(1))) void*)g,
                                   (__attribute__((address_space(3))) void*)l, 16, 0, 0);
}

// ---------------------------------------------------------------- converts
// Fused fp32->bf16 convert of W2 | W_out into ONE contiguous output region
// (W2b | Woutb allocated back-to-back, both multiples of 256 B).
__global__ __launch_bounds__(256) void cvt2_bf16(const float* __restrict__ a,
                                                 const float* __restrict__ b,
                                                 unsigned short* __restrict__ out) {
  const int na4 = (EO * EH) / 4;        // 65536
  int i = blockIdx.x * 256 + threadIdx.x;   // grid sized exactly: 327680 total
  const float* src;
  int off;
  if (i < na4) { src = a; off = i; }
  else         { src = b; off = i - na4; }
  float4 v = ((const float4*)src)[off];
  ushort4 o;
  o.x = f2bf(v.x); o.y = f2bf(v.y); o.z = f2bf(v.z); o.w = f2bf(v.w);
  ((ushort4*)out)[i] = o;
}

// ------------------------------------------------- W1 [EH][V] -> W1T bf16 [V][EH]
__global__ __launch_bounds__(256) void transpose_w1_bf16(const float* __restrict__ W1,
                                                         unsigned short* __restrict__ W1T) {
  __shared__ unsigned short tile[64][72];   // [v][e], padded
  int t = threadIdx.x;
  int v0 = blockIdx.x * 64;
  int e0 = blockIdx.y * 64;
  for (int i = 0; i < 4; ++i) {
    int e = (t >> 4) + i * 16;
    int v = (t & 15) * 4;
    float4 w = *(const float4*)&W1[(size_t)(e0 + e) * V_SZ + v0 + v];
    tile[v + 0][e] = f2bf(w.x);
    tile[v + 1][e] = f2bf(w.y);
    tile[v + 2][e] = f2bf(w.z);
    tile[v + 3][e] = f2bf(w.w);
  }
  __syncthreads();
  for (int i = 0; i < 2; ++i) {
    int v = (t >> 3) + i * 32;
    int e = (t & 7) * 8;
    ushortx8 o;
    for (int j = 0; j < 8; ++j) o[j] = tile[v][e + j];
    *(ushortx8*)&W1T[(size_t)(v0 + v) * EH + e0 + e] = o;
  }
}

// ------------------------------------------------- gather + b1 + threshold -> emb bf16
__global__ __launch_bounds__(256) void gather_emb(const int* __restrict__ ids,
                                                  const unsigned short* __restrict__ W1T,
                                                  const float* __restrict__ b1,
                                                  unsigned short* __restrict__ emb) {
  int t = threadIdx.x;
  int tok = blockIdx.x * 4 + (t >> 6);
  int lane = t & 63;
  int id = ids[tok];
  ushortx8 w = *(const ushortx8*)&W1T[(size_t)id * EH + lane * 8];
  float4 blo = *(const float4*)&b1[lane * 8];
  float4 bhi = *(const float4*)&b1[lane * 8 + 4];
  float bv[8] = {blo.x, blo.y, blo.z, blo.w, bhi.x, bhi.y, bhi.z, bhi.w};
  ushortx8 o;
  for (int j = 0; j < 8; ++j) {
    float x = bf2f(w[j]) + bv[j];
    x = (x > 1e-6f) ? x : 0.0f;
    o[j] = f2bf(x);
  }
  *(ushortx8*)&emb[(size_t)tok * EH + lane * 8] = o;
}

// ------------------------------------------------- MFMA GEMM, C = act(A @ B^T + bias)
// BK=64 + T2 XOR-swizzled LDS (16-B slots, slot ^= row&7); LDS dest of
// global_load_lds stays LINEAR, swizzle applied to the GLOBAL source slot.
template <int ACT, int OUT_BF16>
__global__ __launch_bounds__(256) void gemm_bt(const unsigned short* __restrict__ A,
                                               const unsigned short* __restrict__ B,
                                               const float* __restrict__ bias,
                                               void* __restrict__ Cout,
                                               int M, int N, int K) {
  __shared__ unsigned short lA[128 * 64];   // 16 KB, [row][slot^(row&7)] 16-B slots
  __shared__ unsigned short lB[128 * 64];   // 16 KB
  int t = threadIdx.x;
  int lane = t & 63;
  int wave = t >> 6;
  int bn = blockIdx.x, bm = blockIdx.y;
  int wm = (wave >> 1) * 64;
  int wn = (wave & 1) * 64;
  floatx4 acc[4][4] = {};

  int srow = t >> 3;                       // 0..31 within pass
  int sslot = (t & 7) ^ (srow & 7);        // logical (global) 16-B slot
  int scol = sslot * 8;                    // element offset within BK=64

  const unsigned short* aptr[4];
  const unsigned short* bptr[4];
#pragma unroll
  for (int p = 0; p < 4; ++p) {
    int gra = bm * 128 + p * 32 + srow;  if (gra >= M) gra = M - 1;
    aptr[p] = A + (size_t)gra * K + scol;
    bptr[p] = B + (size_t)(bn * 128 + p * 32 + srow) * K + scol;
  }

  for (int k0 = 0; k0 < K; k0 += 64) {
    __syncthreads();
#pragma unroll
    for (int p = 0; p < 4; ++p) {
      gld_lds16(aptr[p] + k0, &lA[p * 2048 + t * 8]);
      gld_lds16(bptr[p] + k0, &lB[p * 2048 + t * 8]);
    }
    __syncthreads();
#pragma unroll
    for (int kk = 0; kk < 2; ++kk) {
      short8 af[4], bfr[4];
#pragma unroll
      for (int i = 0; i < 4; ++i) {
        int row = wm + i * 16 + (lane & 15);
        int phys = (kk * 4 + (lane >> 4)) ^ (row & 7);
        af[i] = *(const short8*)&lA[row * 64 + phys * 8];
      }
#pragma unroll
      for (int j = 0; j < 4; ++j) {
        int row = wn + j * 16 + (lane & 15);
        int phys = (kk * 4 + (lane >> 4)) ^ (row & 7);
        bfr[j] = *(const short8*)&lB[row * 64 + phys * 8];
      }
#pragma unroll
      for (int i = 0; i < 4; ++i)
#pragma unroll
        for (int j = 0; j < 4; ++j)
          acc[i][j] = __builtin_amdgcn_mfma_f32_16x16x32_bf16(af[i], bfr[j], acc[i][j], 0, 0, 0);
    }
  }

  int rowq = (lane >> 4) * 4;
  for (int j = 0; j < 4; ++j) {
    int col = bn * 128 + wn + j * 16 + (lane & 15);
    float bv = bias[col];
    for (int i = 0; i < 4; ++i) {
      int row0 = bm * 128 + wm + i * 16 + rowq;
      for (int r = 0; r < 4; ++r) {
        int row = row0 + r;
        if (row < M) {
          float v = acc[i][j][r] + bv;
          if (ACT) v = (v > 1e-6f) ? v : 0.0f;
          if (OUT_BF16) ((unsigned short*)Cout)[(size_t)row * N + col] = f2bf(v);
          else          ((float*)Cout)[(size_t)row * N + col] = v;
        }
      }
    }
  }
}

// ------------------------------------------------- W_hh fp32 [3H][H] -> Wprep bf16 in
// MFMA-B-fragment order (see gru_persist).
__global__ __launch_bounds__(256) void prep_whh(const float* __restrict__ W_hh,
                                                unsigned short* __restrict__ Wprep) {
  int tid = blockIdx.x * 256 + threadIdx.x;   // 393216 total
  int lane = tid & 63;
  int c = tid >> 6;          // chunk 0..6143
  int cg = c / 96;
  int r  = c % 96;
  int g  = r >> 5;
  int t  = r & 31;
  int row = g * H_SZ + cg * 16 + (lane & 15);
  int k   = t * 32 + (lane >> 4) * 8;
  const float* src = &W_hh[(size_t)row * H_SZ + k];
  float4 v0 = *(const float4*)src;
  float4 v1 = *(const float4*)(src + 4);
  ushortx8 o;
  o[0] = f2bf(v0.x); o[1] = f2bf(v0.y); o[2] = f2bf(v0.z); o[3] = f2bf(v0.w);
  o[4] = f2bf(v1.x); o[5] = f2bf(v1.y); o[6] = f2bf(v1.z); o[7] = f2bf(v1.w);
  ((ushortx8*)Wprep)[tid] = o;
}

// ------------------------------------------------- W_ih fp32 [3H][EO] -> Wihp bf16 in
// MFMA-B-fragment order, per-cg slices of 48 chunks (3 gates x 16 K-chunks of 32).
__global__ __launch_bounds__(256) void prep_wih(const float* __restrict__ W_ih,
                                                unsigned short* __restrict__ Wihp) {
  int tid = blockIdx.x * 256 + threadIdx.x;   // 196608 total
  int lane = tid & 63;
  int c = tid >> 6;          // chunk 0..3071
  int cg = c / 48;
  int r  = c % 48;
  int g  = r >> 4;
  int kq = r & 15;
  int row = g * H_SZ + cg * 16 + (lane & 15);
  int k   = kq * 32 + (lane >> 4) * 8;
  const float* src = &W_ih[(size_t)row * EO + k];
  float4 v0 = *(const float4*)src;
  float4 v1 = *(const float4*)(src + 4);
  ushortx8 o;
  o[0] = f2bf(v0.x); o[1] = f2bf(v0.y); o[2] = f2bf(v0.z); o[3] = f2bf(v0.w);
  o[4] = f2bf(v1.x); o[5] = f2bf(v1.y); o[6] = f2bf(v1.z); o[7] = f2bf(v1.w);
  ((ushortx8*)Wihp)[tid] = o;
}

// ------------------------------------------------- persistent GRU recurrence
// 256 blocks x 256 threads, cooperative. Block (bg,cg): batches [bg*16,+16),
// h-cols [cg*16,+16), all 3 gates; wave w = K-quarter [w*256,+256).
// Barrier: EXACT round-0 form (measured 2.93 us/step): per-bg monotonic
// fetch_add counter + single-lane s_sleep(2) poll. Four alternative barrier
// schemes (rounds 1/2/4) all regressed -- do not touch.
//
// xW fold (round-5) + ASYNC SPLIT (round-6, T14): round-5 folded the
// xW = x @ W_ih^T GEMM into the barrier wait window but issued the 16 x-loads
// INSIDE the window -> serialized load->MFMA chain added ~0.8 us/step.
// Fix: issue the x[s+1] loads (pinned inline-asm global_load_dwordx4) right
// after the main W_hh MFMA block of step s; they complete under the lgh
// stores + gate math + drain barrier (which waits vmcnt(0) anyway). The wait
// window then runs pure LDS-read + 16 MFMA (~300 cy), fully hidden under the
// ~2000-cy poll.
__global__ __launch_bounds__(256, 1) void gru_persist(const unsigned short* __restrict__ hprep0,
                                                      unsigned short* __restrict__ hprep1,
                                                      unsigned short* __restrict__ hbfinal,
                                                      const unsigned short* __restrict__ Wprep,
                                                      const unsigned short* __restrict__ Wihp,
                                                      const float* __restrict__ b_hh,
                                                      const float* __restrict__ b_ih,
                                                      const unsigned short* __restrict__ x,
                                                      unsigned* __restrict__ bar) {
  __shared__ unsigned short lB[96 * 512];    // 98304 B : W_hh slice, fragment order
  __shared__ unsigned short lWih[48 * 512];  // 49152 B : W_ih slice, fragment order
  __shared__ float lgh[3][4][256];           // 12288 B : per-wave K-partials
  __shared__ float lgx[3][256];              //  3072 B : xW tile for next step
  // total 162816 B of 163840 B LDS
  int t = threadIdx.x;
  int lane = t & 63;
  int w = t >> 6;
  int bg = blockIdx.x >> 6;    // 0..3
  int cg = blockIdx.x & 63;    // 0..63

  // stage W_hh slice once (identity copy, 98 KB)
  const unsigned short* wsrc = Wprep + (size_t)cg * 96 * 512;
  for (int i = 0; i < 24; ++i) {
    int c = w * 24 + i;
    gld_lds16(wsrc + (size_t)c * 512 + lane * 8, &lB[c * 512 + lane * 8]);
  }
  // stage W_ih slice once (48 KB)
  const unsigned short* wxs = Wihp + (size_t)cg * 48 * 512;
  for (int i = 0; i < 12; ++i) {
    int c = w * 12 + i;
    gld_lds16(wxs + (size_t)c * 512 + lane * 8, &lWih[c * 512 + lane * 8]);
  }

  // per-thread update-element constants
  int b_loc = t >> 4;
  int j_loc = t & 15;
  int jcol = cg * 16 + j_loc;          // h column
  int bglob = bg * 16 + b_loc;         // batch
  float bhr = b_hh[jcol];
  float bhz = b_hh[H_SZ + jcol];
  float bhn = b_hh[2 * H_SZ + jcol];
  float bihr = b_ih[jcol];
  float bihz = b_ih[H_SZ + jcol];
  float bihn = b_ih[2 * H_SZ + jcol];
  // scatter-store position for h_new (A-fragment layout); lane pairs (jj even/odd)
  // pack 2 bf16 into one dword store.
  int tt2 = jcol >> 5;
  int q   = (jcol >> 3) & 3;
  int jj  = jcol & 7;
  int Ls  = b_loc | (q << 4);
  size_t hw_off32 = ((((size_t)(bg * 32 + tt2) * 64 + Ls) * 8) + (jj & ~1)) >> 1;

  const unsigned short* hbufs[2] = {hprep0, hprep1};
  unsigned* barp = bar + bg * 64;      // per-bg counter, 256 B apart
  float hmaster = 0.0f;                // fp32 master h for my (batch, col)

  // per-lane base for xW A-fragments (batch = lane&15, k0 = (lane>>4)*8)
  const unsigned short* xbase = x + ((size_t)(bg * 16 + (lane & 15))) * EO + (lane >> 4) * 8;

  // prologue-only: xW tile for s=0 with in-window loads (off critical path)
  auto xw_compute0 = [&]() {
    int g = w - 1;
    floatx4 accx = {};
#pragma unroll
    for (int kq = 0; kq < 16; ++kq) {
      uintx4 xv = *(const uintx4*)(xbase + kq * 32);
      short8 a = __builtin_bit_cast(short8, xv);
      short8 bfr = *(const short8*)&lWih[((g * 16 + kq) * 64 + lane) * 8];
      accx = __builtin_amdgcn_mfma_f32_16x16x32_bf16(a, bfr, accx, 0, 0, 0);
    }
#pragma unroll
    for (int r = 0; r < 4; ++r)
      lgx[g][((lane >> 4) * 4 + r) * 16 + (lane & 15)] = accx[r];
  };

  __syncthreads();   // drains staging vmcnt (lB + lWih ready)

  if (w >= 1) xw_compute0();
  __syncthreads();
  float xr = lgx[0][t] + bihr;
  float xz = lgx[1][t] + bihz;
  float xn = lgx[2][t] + bihn;

  for (int s = 0; s < S_LEN; ++s) {
    const unsigned short* hr = hbufs[s & 1];
    unsigned* hw32 = (unsigned*)hbufs[(s + 1) & 1];

    // A-fragments for my K-quarter: 8 x 16B coherent (sc1) loads, pipelined,
    // one tied waitcnt. Bypasses stale L1/L2 without any cache-wide inv.
    uintx4 av[8];
#pragma unroll
    for (int i = 0; i < 8; ++i) {
      int tt = w * 8 + i;
      const void* ap = hr + ((size_t)(bg * 32 + tt) * 64 + lane) * 8;
      asm volatile("global_load_dwordx4 %0, %1, off sc1" : "=v"(av[i]) : "v"(ap));
    }
    asm volatile("s_waitcnt vmcnt(0)"
                 : "+v"(av[0]), "+v"(av[1]), "+v"(av[2]), "+v"(av[3]),
                   "+v"(av[4]), "+v"(av[5]), "+v"(av[6]), "+v"(av[7])
                 :: "memory");

    floatx4 acc[3] = {};
#pragma unroll
    for (int i = 0; i < 8; ++i) {
      int tt = w * 8 + i;
      short8 a = __builtin_bit_cast(short8, av[i]);
#pragma unroll
      for (int g = 0; g < 3; ++g) {
        short8 bfr = *(const short8*)&lB[((g * 32 + tt) * 64 + lane) * 8];
        acc[g] = __builtin_amdgcn_mfma_f32_16x16x32_bf16(a, bfr, acc[g], 0, 0, 0);
      }
    }

    // T14 issue-early: x[s+1] A-fragments as pinned asm loads (waves 1-3).
    // They drain at the pre-arrive __syncthreads (vmcnt(0)) -> ready in the
    // wait window with zero in-window latency. Fully unrolled => static
    // indexing, stays in VGPRs (launch_bounds(256,1) lifts the reg cap).
    uintx4 xf[16];
    if (w >= 1 && s + 1 < S_LEN) {
      const unsigned short* xrow = xbase + (size_t)(s + 1) * B_SZ * EO;
#pragma unroll
      for (int kq = 0; kq < 16; ++kq)
        asm volatile("global_load_dwordx4 %0, %1, off" : "=v"(xf[kq]) : "v"(xrow + kq * 32));
    }

#pragma unroll
    for (int g = 0; g < 3; ++g)
#pragma unroll
      for (int r = 0; r < 4; ++r)
        lgh[g][w][((lane >> 4) * 4 + r) * 16 + (lane & 15)] = acc[g][r];
    __syncthreads();

    // gate update for my element (sum 4 K-partials)
    float ghr = lgh[0][0][t] + lgh[0][1][t] + lgh[0][2][t] + lgh[0][3][t] + bhr;
    float ghz = lgh[1][0][t] + lgh[1][1][t] + lgh[1][2][t] + lgh[1][3][t] + bhz;
    float ghn = lgh[2][0][t] + lgh[2][1][t] + lgh[2][2][t] + lgh[2][3][t] + bhn;
    float rr = 1.0f / (1.0f + __expf(-(xr + ghr)));
    float zz = 1.0f / (1.0f + __expf(-(xz + ghz)));
    float nn = tanhf(xn + rr * ghn);
    float hnew = (1.0f - zz) * nn + zz * hmaster;
    hmaster = hnew;

    unsigned hb = (unsigned)f2bf(hnew);
    unsigned other = (unsigned)__shfl_xor((int)hb, 1);
    if ((jj & 1) == 0) {
      unsigned packed = hb | (other << 16);   // (jj, jj+1)
      __hip_atomic_store(hw32 + hw_off32, packed,
                         __ATOMIC_RELAXED, __HIP_MEMORY_SCOPE_AGENT);
    }
    if (s == S_LEN - 1) hbfinal[(size_t)bglob * H_SZ + jcol] = (unsigned short)hb;

    if (s < S_LEN - 1) {
      __syncthreads();   // waitcnt vmcnt(0) + barrier: h-stores at L3, xf loaded
      if (w == 0) {
        if (t == 0) {
          __hip_atomic_fetch_add(barp, 1u, __ATOMIC_RELAXED, __HIP_MEMORY_SCOPE_AGENT);
          unsigned target = 64u * (unsigned)(s + 1);
          while (__hip_atomic_load(barp, __ATOMIC_RELAXED, __HIP_MEMORY_SCOPE_AGENT) < target)
            __builtin_amdgcn_s_sleep(2);
        }
      } else {
        // wait window: consume prefetched xf (pure LDS + MFMA, ~300 cy)
        asm volatile("s_waitcnt vmcnt(0)" ::: "memory");   // no-op: drained above
        __builtin_amdgcn_sched_barrier(0);
        int g = w - 1;
        floatx4 accx = {};
#pragma unroll
        for (int kq = 0; kq < 16; ++kq) {
          short8 a = __builtin_bit_cast(short8, xf[kq]);
          short8 bfr = *(const short8*)&lWih[((g * 16 + kq) * 64 + lane) * 8];
          accx = __builtin_amdgcn_mfma_f32_16x16x32_bf16(a, bfr, accx, 0, 0, 0);
        }
#pragma unroll
        for (int r = 0; r < 4; ++r)
          lgx[g][((lane >> 4) * 4 + r) * 16 + (lane & 15)] = accx[r];
      }
      __syncthreads();   // release; also publishes lgx
      xr = lgx[0][t] + bihr;
      xz = lgx[1][t] + bihz;
      xn = lgx[2][t] + bihn;
    }
  }
}

// ----------------------------------------------------------------- launch
extern "C" void kernel_launch(void* const* d_in, const int* in_sizes, int n_in,
                              void* d_out, int out_size, void* d_ws, size_t ws_size,
                              hipStream_t stream) {
  const int*   ids   = (const int*)d_in[0];
  const float* W1    = (const float*)d_in[1];
  const float* b1    = (const float*)d_in[2];
  const float* W2    = (const float*)d_in[3];
  const float* b2    = (const float*)d_in[4];
  const float* W_ih  = (const float*)d_in[5];
  const float* b_ih  = (const float*)d_in[6];
  const float* W_hh  = (const float*)d_in[7];
  const float* b_hh  = (const float*)d_in[8];
  const float* W_out = (const float*)d_in[9];
  const float* b_out = (const float*)d_in[10];
  float* out = (float*)d_out;

  uint8_t* wsp = (uint8_t*)d_ws;
  auto alloc = [&](size_t bytes) {
    uint8_t* p = wsp;
    wsp += (bytes + 255) & ~(size_t)255;
    return p;
  };
  unsigned short* W1T   = (unsigned short*)alloc((size_t)V_SZ * EH * 2);
  // NOTE: W2b/Woutb must stay contiguous & in this order (cvt2_bf16 fuses
  // both converts into one launch over the concatenated region).
  unsigned short* W2b   = (unsigned short*)alloc((size_t)EO * EH * 2);
  unsigned short* Woutb = (unsigned short*)alloc((size_t)O_SZ * H_SZ * 2);
  unsigned short* Wprep = (unsigned short*)alloc((size_t)G3 * H_SZ * 2);
  unsigned short* Wihp  = (unsigned short*)alloc((size_t)G3 * EO * 2);
  unsigned short* emb   = (unsigned short*)alloc((size_t)S_LEN * B_SZ * EH * 2);
  unsigned short* x     = (unsigned short*)alloc((size_t)S_LEN * B_SZ * EO * 2);
  unsigned short* hprep0 = (unsigned short*)alloc((size_t)B_SZ * H_SZ * 2);
  unsigned short* hprep1 = (unsigned short*)alloc((size_t)B_SZ * H_SZ * 2);
  unsigned short* hbfinal = (unsigned short*)alloc((size_t)B_SZ * H_SZ * 2);
  unsigned*       bar     = (unsigned*)alloc(1024);

  // fused weight converts (fp32 -> bf16): W2 | W_out -> one launch
  cvt2_bf16<<<dim3(1280), 256, 0, stream>>>(W2, W_out, W2b);

  // W_hh / W_ih -> MFMA-fragment-ordered bf16
  prep_whh<<<dim3(1536), 256, 0, stream>>>(W_hh, Wprep);
  prep_wih<<<dim3(768), 256, 0, stream>>>(W_ih, Wihp);

  // zero h0 (fragment-layout buffer read at s=0) and the 4 barrier counters
  hipMemsetAsync(hprep0, 0, (size_t)B_SZ * H_SZ * 2, stream);
  hipMemsetAsync(bar, 0, 1024, stream);

  // W1 transpose -> bf16
  transpose_w1_bf16<<<dim3(V_SZ / 64, EH / 64), 256, 0, stream>>>(W1, W1T);

  // embedding gather + b1 + threshold
  gather_emb<<<dim3(S_LEN * B_SZ / 4), 256, 0, stream>>>(ids, W1T, b1, emb);

  // x = thresh(emb @ W2^T + b2)
  gemm_bt<1, 1><<<dim3(EO / 128, S_LEN * B_SZ / 128), 256, 0, stream>>>(
      emb, W2b, b2, x, S_LEN * B_SZ, EO, EH);

  // persistent GRU recurrence (cooperative: all 256 blocks co-resident)
  // xW GEMM folded inside (issue-early/consume-late in the wait window).
  {
    void* args[] = {(void*)&hprep0, (void*)&hprep1, (void*)&hbfinal,
                    (void*)&Wprep, (void*)&Wihp, (void*)&b_hh, (void*)&b_ih,
                    (void*)&x, (void*)&bar};
    hipLaunchCooperativeKernel((const void*)gru_persist, dim3(256), dim3(256),
                               args, 0, stream);
  }

  // out = h @ W_out^T + b_out
  gemm_bt<0, 0><<<dim3(O_SZ / 128, 1), 256, 0, stream>>>(
      hbfinal, Woutb, b_out, out, B_SZ, O_SZ, H_SZ);
}

// Round 7
// 620.993 us; speedup vs baseline: 1.1857x; 1.0868x over previous
//
#include <hip/hip_runtime.h>
#include <stdint.h>
#include <stddef.h>

// Problem constants
#define S_LEN 128
#define B_SZ  64
#define V_SZ  32000
#define EH    512
#define EO    512
#define H_SZ  1024
#define O_SZ  1024
#define G3    3072   // 3*H

typedef __attribute__((ext_vector_type(8))) short short8;
typedef __attribute__((ext_vector_type(4))) float floatx4;
typedef __attribute__((ext_vector_type(8))) unsigned short ushortx8;
typedef __attribute__((ext_vector_type(4))) unsigned uintx4;

__device__ __forceinline__ unsigned short f2bf(float f) {
  unsigned u = __builtin_bit_cast(unsigned, f);
  u += 0x7FFFu + ((u >> 16) & 1u);   // round-to-nearest-even
  return (unsigned short)(u >> 16);
}
__device__ __forceinline__ float bf2f(unsigned short h) {
  unsigned u = ((unsigned)h) << 16;
  return __builtin_bit_cast(float, u);
}

__device__ __forceinline__ void gld_lds16(const void* g, void* l) {
  __builtin_amdgcn_global_load_lds((const __attribute__((address_space(1))) void*)g,
                                   (__attribute__((address_space(3))) void*)l, 16, 0, 0);
}

// ---------------------------------------------------------------- converts
// Fused fp32->bf16 convert of W2 | W_out into ONE contiguous output region
// (W2b | Woutb allocated back-to-back, both multiples of 256 B).
__global__ __launch_bounds__(256) void cvt2_bf16(const float* __restrict__ a,
                                                 const float* __restrict__ b,
                                                 unsigned short* __restrict__ out) {
  const int na4 = (EO * EH) / 4;        // 65536
  int i = blockIdx.x * 256 + threadIdx.x;   // grid sized exactly: 327680 total
  const float* src;
  int off;
  if (i < na4) { src = a; off = i; }
  else         { src = b; off = i - na4; }
  float4 v = ((const float4*)src)[off];
  ushort4 o;
  o.x = f2bf(v.x); o.y = f2bf(v.y); o.z = f2bf(v.z); o.w = f2bf(v.w);
  ((ushort4*)out)[i] = o;
}

// ------------------------------------------------- W1 [EH][V] -> W1T bf16 [V][EH]
__global__ __launch_bounds__(256) void transpose_w1_bf16(const float* __restrict__ W1,
                                                         unsigned short* __restrict__ W1T) {
  __shared__ unsigned short tile[64][72];   // [v][e], padded
  int t = threadIdx.x;
  int v0 = blockIdx.x * 64;
  int e0 = blockIdx.y * 64;
  for (int i = 0; i < 4; ++i) {
    int e = (t >> 4) + i * 16;
    int v = (t & 15) * 4;
    float4 w = *(const float4*)&W1[(size_t)(e0 + e) * V_SZ + v0 + v];
    tile[v + 0][e] = f2bf(w.x);
    tile[v + 1][e] = f2bf(w.y);
    tile[v + 2][e] = f2bf(w.z);
    tile[v + 3][e] = f2bf(w.w);
  }
  __syncthreads();
  for (int i = 0; i < 2; ++i) {
    int v = (t >> 3) + i * 32;
    int e = (t & 7) * 8;
    ushortx8 o;
    for (int j = 0; j < 8; ++j) o[j] = tile[v][e + j];
    *(ushortx8*)&W1T[(size_t)(v0 + v) * EH + e0 + e] = o;
  }
}

// ------------------------------------------------- gather + b1 + threshold -> emb bf16
__global__ __launch_bounds__(256) void gather_emb(const int* __restrict__ ids,
                                                  const unsigned short* __restrict__ W1T,
                                                  const float* __restrict__ b1,
                                                  unsigned short* __restrict__ emb) {
  int t = threadIdx.x;
  int tok = blockIdx.x * 4 + (t >> 6);
  int lane = t & 63;
  int id = ids[tok];
  ushortx8 w = *(const ushortx8*)&W1T[(size_t)id * EH + lane * 8];
  float4 blo = *(const float4*)&b1[lane * 8];
  float4 bhi = *(const float4*)&b1[lane * 8 + 4];
  float bv[8] = {blo.x, blo.y, blo.z, blo.w, bhi.x, bhi.y, bhi.z, bhi.w};
  ushortx8 o;
  for (int j = 0; j < 8; ++j) {
    float x = bf2f(w[j]) + bv[j];
    x = (x > 1e-6f) ? x : 0.0f;
    o[j] = f2bf(x);
  }
  *(ushortx8*)&emb[(size_t)tok * EH + lane * 8] = o;
}

// ------------------------------------------------- MFMA GEMM, C = act(A @ B^T + bias)
// BK=64 + T2 XOR-swizzled LDS (16-B slots, slot ^= row&7); LDS dest of
// global_load_lds stays LINEAR, swizzle applied to the GLOBAL source slot.
template <int ACT, int OUT_BF16>
__global__ __launch_bounds__(256) void gemm_bt(const unsigned short* __restrict__ A,
                                               const unsigned short* __restrict__ B,
                                               const float* __restrict__ bias,
                                               void* __restrict__ Cout,
                                               int M, int N, int K) {
  __shared__ unsigned short lA[128 * 64];   // 16 KB, [row][slot^(row&7)] 16-B slots
  __shared__ unsigned short lB[128 * 64];   // 16 KB
  int t = threadIdx.x;
  int lane = t & 63;
  int wave = t >> 6;
  int bn = blockIdx.x, bm = blockIdx.y;
  int wm = (wave >> 1) * 64;
  int wn = (wave & 1) * 64;
  floatx4 acc[4][4] = {};

  int srow = t >> 3;                       // 0..31 within pass
  int sslot = (t & 7) ^ (srow & 7);        // logical (global) 16-B slot
  int scol = sslot * 8;                    // element offset within BK=64

  const unsigned short* aptr[4];
  const unsigned short* bptr[4];
#pragma unroll
  for (int p = 0; p < 4; ++p) {
    int gra = bm * 128 + p * 32 + srow;  if (gra >= M) gra = M - 1;
    aptr[p] = A + (size_t)gra * K + scol;
    bptr[p] = B + (size_t)(bn * 128 + p * 32 + srow) * K + scol;
  }

  for (int k0 = 0; k0 < K; k0 += 64) {
    __syncthreads();
#pragma unroll
    for (int p = 0; p < 4; ++p) {
      gld_lds16(aptr[p] + k0, &lA[p * 2048 + t * 8]);
      gld_lds16(bptr[p] + k0, &lB[p * 2048 + t * 8]);
    }
    __syncthreads();
#pragma unroll
    for (int kk = 0; kk < 2; ++kk) {
      short8 af[4], bfr[4];
#pragma unroll
      for (int i = 0; i < 4; ++i) {
        int row = wm + i * 16 + (lane & 15);
        int phys = (kk * 4 + (lane >> 4)) ^ (row & 7);
        af[i] = *(const short8*)&lA[row * 64 + phys * 8];
      }
#pragma unroll
      for (int j = 0; j < 4; ++j) {
        int row = wn + j * 16 + (lane & 15);
        int phys = (kk * 4 + (lane >> 4)) ^ (row & 7);
        bfr[j] = *(const short8*)&lB[row * 64 + phys * 8];
      }
#pragma unroll
      for (int i = 0; i < 4; ++i)
#pragma unroll
        for (int j = 0; j < 4; ++j)
          acc[i][j] = __builtin_amdgcn_mfma_f32_16x16x32_bf16(af[i], bfr[j], acc[i][j], 0, 0, 0);
    }
  }

  int rowq = (lane >> 4) * 4;
  for (int j = 0; j < 4; ++j) {
    int col = bn * 128 + wn + j * 16 + (lane & 15);
    float bv = bias[col];
    for (int i = 0; i < 4; ++i) {
      int row0 = bm * 128 + wm + i * 16 + rowq;
      for (int r = 0; r < 4; ++r) {
        int row = row0 + r;
        if (row < M) {
          float v = acc[i][j][r] + bv;
          if (ACT) v = (v > 1e-6f) ? v : 0.0f;
          if (OUT_BF16) ((unsigned short*)Cout)[(size_t)row * N + col] = f2bf(v);
          else          ((float*)Cout)[(size_t)row * N + col] = v;
        }
      }
    }
  }
}

// ------------------------------------------------- W_hh fp32 [3H][H] -> Wprep bf16 in
// MFMA-B-fragment order (see gru_persist).
__global__ __launch_bounds__(256) void prep_whh(const float* __restrict__ W_hh,
                                                unsigned short* __restrict__ Wprep) {
  int tid = blockIdx.x * 256 + threadIdx.x;   // 393216 total
  int lane = tid & 63;
  int c = tid >> 6;          // chunk 0..6143
  int cg = c / 96;
  int r  = c % 96;
  int g  = r >> 5;
  int t  = r & 31;
  int row = g * H_SZ + cg * 16 + (lane & 15);
  int k   = t * 32 + (lane >> 4) * 8;
  const float* src = &W_hh[(size_t)row * H_SZ + k];
  float4 v0 = *(const float4*)src;
  float4 v1 = *(const float4*)(src + 4);
  ushortx8 o;
  o[0] = f2bf(v0.x); o[1] = f2bf(v0.y); o[2] = f2bf(v0.z); o[3] = f2bf(v0.w);
  o[4] = f2bf(v1.x); o[5] = f2bf(v1.y); o[6] = f2bf(v1.z); o[7] = f2bf(v1.w);
  ((ushortx8*)Wprep)[tid] = o;
}

// ------------------------------------------------- W_ih fp32 [3H][EO] -> Wihp bf16 in
// MFMA-B-fragment order, per-cg slices of 48 chunks (3 gates x 16 K-chunks of 32).
__global__ __launch_bounds__(256) void prep_wih(const float* __restrict__ W_ih,
                                                unsigned short* __restrict__ Wihp) {
  int tid = blockIdx.x * 256 + threadIdx.x;   // 196608 total
  int lane = tid & 63;
  int c = tid >> 6;          // chunk 0..3071
  int cg = c / 48;
  int r  = c % 48;
  int g  = r >> 4;
  int kq = r & 15;
  int row = g * H_SZ + cg * 16 + (lane & 15);
  int k   = kq * 32 + (lane >> 4) * 8;
  const float* src = &W_ih[(size_t)row * EO + k];
  float4 v0 = *(const float4*)src;
  float4 v1 = *(const float4*)(src + 4);
  ushortx8 o;
  o[0] = f2bf(v0.x); o[1] = f2bf(v0.y); o[2] = f2bf(v0.z); o[3] = f2bf(v0.w);
  o[4] = f2bf(v1.x); o[5] = f2bf(v1.y); o[6] = f2bf(v1.z); o[7] = f2bf(v1.w);
  ((ushortx8*)Wihp)[tid] = o;
}

// ------------------------------------------------- persistent GRU recurrence
// 256 blocks x 256 threads, cooperative. Block (bg,cg): batches [bg*16,+16),
// h-cols [cg*16,+16), all 3 gates; wave w = K-quarter [w*256,+256).
// Barrier: EXACT round-0 form (measured 2.93 us/step): per-bg monotonic
// fetch_add counter + single-lane s_sleep(2) poll, EMPTY wait window.
// Four alternative barrier schemes (rounds 1/2/4) all regressed -- frozen.
//
// xW fold, round-7 form: the xW = x @ W_ih^T MFMAs run inside the MAIN MFMA
// block (matrix pipe has idle slots there), spread over all 4 waves: wave w
// owns kq in [4w,4w+4) for all 3 gates (12 MFMA). For gates r,z the xW
// product accumulates into the SAME accumulator as W_hh (reference only uses
// sigmoid(x_g + h_g); biases merged). Gate n needs xW separate (tanh(xn +
// r*ghn)) -> one extra 4-KB partial buffer lgxn. x A-fragments (xf[4], 16
// VGPR) are prefetched ONE FULL STEP ahead (issued right after the MFMA
// block, ~7000 cy cover) and tied into the main vmcnt(0) (rule #18).
// Wait window is EMPTY again (round-6's in-window xw_compute removed).
__global__ __launch_bounds__(256, 1) void gru_persist(const unsigned short* __restrict__ hprep0,
                                                      unsigned short* __restrict__ hprep1,
                                                      unsigned short* __restrict__ hbfinal,
                                                      const unsigned short* __restrict__ Wprep,
                                                      const unsigned short* __restrict__ Wihp,
                                                      const float* __restrict__ b_hh,
                                                      const float* __restrict__ b_ih,
                                                      const unsigned short* __restrict__ x,
                                                      unsigned* __restrict__ bar) {
  __shared__ unsigned short lB[96 * 512];    // 98304 B : W_hh slice, fragment order
  __shared__ unsigned short lWih[48 * 512];  // 49152 B : W_ih slice, fragment order
  __shared__ float lgh[3][4][256];           // 12288 B : per-wave K-partials (r,z merged)
  __shared__ float lgxn[4][256];             //  4096 B : per-wave xW n-gate partials
  // total 163840 B = full 160 KiB LDS
  int t = threadIdx.x;
  int lane = t & 63;
  int w = t >> 6;
  int bg = blockIdx.x >> 6;    // 0..3
  int cg = blockIdx.x & 63;    // 0..63

  // stage W_hh slice once (identity copy, 98 KB)
  const unsigned short* wsrc = Wprep + (size_t)cg * 96 * 512;
  for (int i = 0; i < 24; ++i) {
    int c = w * 24 + i;
    gld_lds16(wsrc + (size_t)c * 512 + lane * 8, &lB[c * 512 + lane * 8]);
  }
  // stage W_ih slice once (48 KB)
  const unsigned short* wxs = Wihp + (size_t)cg * 48 * 512;
  for (int i = 0; i < 12; ++i) {
    int c = w * 12 + i;
    gld_lds16(wxs + (size_t)c * 512 + lane * 8, &lWih[c * 512 + lane * 8]);
  }

  // per-thread update-element constants
  int b_loc = t >> 4;
  int j_loc = t & 15;
  int jcol = cg * 16 + j_loc;          // h column
  int bglob = bg * 16 + b_loc;         // batch
  float brz_r = b_hh[jcol] + b_ih[jcol];                    // merged r bias
  float brz_z = b_hh[H_SZ + jcol] + b_ih[H_SZ + jcol];      // merged z bias
  float bhn  = b_hh[2 * H_SZ + jcol];
  float bihn = b_ih[2 * H_SZ + jcol];
  // scatter-store position for h_new (A-fragment layout); lane pairs (jj even/odd)
  // pack 2 bf16 into one dword store.
  int tt2 = jcol >> 5;
  int q   = (jcol >> 3) & 3;
  int jj  = jcol & 7;
  int Ls  = b_loc | (q << 4);
  size_t hw_off32 = ((((size_t)(bg * 32 + tt2) * 64 + Ls) * 8) + (jj & ~1)) >> 1;

  const unsigned short* hbufs[2] = {hprep0, hprep1};
  unsigned* barp = bar + bg * 64;      // per-bg counter, 256 B apart
  float hmaster = 0.0f;                // fp32 master h for my (batch, col)

  // per-lane base for xW A-fragments (batch = lane&15, k0 = (lane>>4)*8);
  // wave w owns kq = 4w..4w+3  -> element offset kq*32
  const unsigned short* xbase =
      x + ((size_t)(bg * 16 + (lane & 15))) * EO + (lane >> 4) * 8 + (w * 4) * 32;

  __syncthreads();   // drains staging vmcnt (lB + lWih ready)

  // prologue: issue xf prefetch for s=0 (consumed at the s=0 main block;
  // the loop's tied vmcnt(0) waits for them)
  uintx4 xf[4];
#pragma unroll
  for (int i = 0; i < 4; ++i)
    asm volatile("global_load_dwordx4 %0, %1, off" : "=v"(xf[i]) : "v"(xbase + i * 32));

  for (int s = 0; s < S_LEN; ++s) {
    const unsigned short* hr = hbufs[s & 1];
    unsigned* hw32 = (unsigned*)hbufs[(s + 1) & 1];

    // A-fragments for my K-quarter: 8 x 16B coherent (sc1) loads, pipelined,
    // one tied waitcnt (also ties xf: prevents xW-MFMA hoisting, rule #18).
    uintx4 av[8];
#pragma unroll
    for (int i = 0; i < 8; ++i) {
      int tt = w * 8 + i;
      const void* ap = hr + ((size_t)(bg * 32 + tt) * 64 + lane) * 8;
      asm volatile("global_load_dwordx4 %0, %1, off sc1" : "=v"(av[i]) : "v"(ap));
    }
    asm volatile("s_waitcnt vmcnt(0)"
                 : "+v"(av[0]), "+v"(av[1]), "+v"(av[2]), "+v"(av[3]),
                   "+v"(av[4]), "+v"(av[5]), "+v"(av[6]), "+v"(av[7]),
                   "+v"(xf[0]), "+v"(xf[1]), "+v"(xf[2]), "+v"(xf[3])
                 :: "memory");

    // main MFMA block: 24 W_hh MFMAs + 12 xW MFMAs (r,z merged into acc[0/1])
    floatx4 acc[3] = {};
    floatx4 accn = {};
#pragma unroll
    for (int i = 0; i < 8; ++i) {
      int tt = w * 8 + i;
      short8 a = __builtin_bit_cast(short8, av[i]);
#pragma unroll
      for (int g = 0; g < 3; ++g) {
        short8 bfr = *(const short8*)&lB[((g * 32 + tt) * 64 + lane) * 8];
        acc[g] = __builtin_amdgcn_mfma_f32_16x16x32_bf16(a, bfr, acc[g], 0, 0, 0);
      }
    }
#pragma unroll
    for (int i = 0; i < 4; ++i) {
      int kq = w * 4 + i;
      short8 a = __builtin_bit_cast(short8, xf[i]);
      short8 b0 = *(const short8*)&lWih[((0 * 16 + kq) * 64 + lane) * 8];
      short8 b1 = *(const short8*)&lWih[((1 * 16 + kq) * 64 + lane) * 8];
      short8 b2 = *(const short8*)&lWih[((2 * 16 + kq) * 64 + lane) * 8];
      acc[0] = __builtin_amdgcn_mfma_f32_16x16x32_bf16(a, b0, acc[0], 0, 0, 0);
      acc[1] = __builtin_amdgcn_mfma_f32_16x16x32_bf16(a, b1, acc[1], 0, 0, 0);
      accn   = __builtin_amdgcn_mfma_f32_16x16x32_bf16(a, b2, accn,   0, 0, 0);
    }

    // prefetch x A-fragments for step s+1 (full-step cover, 4 loads/thread)
    if (s + 1 < S_LEN) {
      const unsigned short* xrow = xbase + (size_t)(s + 1) * B_SZ * EO;
#pragma unroll
      for (int i = 0; i < 4; ++i)
        asm volatile("global_load_dwordx4 %0, %1, off" : "=v"(xf[i]) : "v"(xrow + i * 32));
    }

#pragma unroll
    for (int g = 0; g < 3; ++g)
#pragma unroll
      for (int r = 0; r < 4; ++r)
        lgh[g][w][((lane >> 4) * 4 + r) * 16 + (lane & 15)] = acc[g][r];
#pragma unroll
    for (int r = 0; r < 4; ++r)
      lgxn[w][((lane >> 4) * 4 + r) * 16 + (lane & 15)] = accn[r];
    __syncthreads();

    // gate update for my element (sum 4 K-partials; r,z already merged)
    float grs = lgh[0][0][t] + lgh[0][1][t] + lgh[0][2][t] + lgh[0][3][t] + brz_r;
    float gzs = lgh[1][0][t] + lgh[1][1][t] + lgh[1][2][t] + lgh[1][3][t] + brz_z;
    float ghn = lgh[2][0][t] + lgh[2][1][t] + lgh[2][2][t] + lgh[2][3][t] + bhn;
    float xnv = lgxn[0][t] + lgxn[1][t] + lgxn[2][t] + lgxn[3][t] + bihn;
    float rr = 1.0f / (1.0f + __expf(-grs));
    float zz = 1.0f / (1.0f + __expf(-gzs));
    float nn = tanhf(xnv + rr * ghn);
    float hnew = (1.0f - zz) * nn + zz * hmaster;
    hmaster = hnew;

    unsigned hb = (unsigned)f2bf(hnew);
    unsigned other = (unsigned)__shfl_xor((int)hb, 1);
    if ((jj & 1) == 0) {
      unsigned packed = hb | (other << 16);   // (jj, jj+1)
      __hip_atomic_store(hw32 + hw_off32, packed,
                         __ATOMIC_RELAXED, __HIP_MEMORY_SCOPE_AGENT);
    }
    if (s == S_LEN - 1) hbfinal[(size_t)bglob * H_SZ + jcol] = (unsigned short)hb;

    if (s < S_LEN - 1) {
      __syncthreads();   // waitcnt vmcnt(0) + barrier: h-stores at L3, xf loaded
      if (t == 0) {
        __hip_atomic_fetch_add(barp, 1u, __ATOMIC_RELAXED, __HIP_MEMORY_SCOPE_AGENT);
        unsigned target = 64u * (unsigned)(s + 1);
        while (__hip_atomic_load(barp, __ATOMIC_RELAXED, __HIP_MEMORY_SCOPE_AGENT) < target)
          __builtin_amdgcn_s_sleep(2);
      }
      __syncthreads();   // release
    }
  }
}

// ----------------------------------------------------------------- launch
extern "C" void kernel_launch(void* const* d_in, const int* in_sizes, int n_in,
                              void* d_out, int out_size, void* d_ws, size_t ws_size,
                              hipStream_t stream) {
  const int*   ids   = (const int*)d_in[0];
  const float* W1    = (const float*)d_in[1];
  const float* b1    = (const float*)d_in[2];
  const float* W2    = (const float*)d_in[3];
  const float* b2    = (const float*)d_in[4];
  const float* W_ih  = (const float*)d_in[5];
  const float* b_ih  = (const float*)d_in[6];
  const float* W_hh  = (const float*)d_in[7];
  const float* b_hh  = (const float*)d_in[8];
  const float* W_out = (const float*)d_in[9];
  const float* b_out = (const float*)d_in[10];
  float* out = (float*)d_out;

  uint8_t* wsp = (uint8_t*)d_ws;
  auto alloc = [&](size_t bytes) {
    uint8_t* p = wsp;
    wsp += (bytes + 255) & ~(size_t)255;
    return p;
  };
  unsigned short* W1T   = (unsigned short*)alloc((size_t)V_SZ * EH * 2);
  // NOTE: W2b/Woutb must stay contiguous & in this order (cvt2_bf16 fuses
  // both converts into one launch over the concatenated region).
  unsigned short* W2b   = (unsigned short*)alloc((size_t)EO * EH * 2);
  unsigned short* Woutb = (unsigned short*)alloc((size_t)O_SZ * H_SZ * 2);
  unsigned short* Wprep = (unsigned short*)alloc((size_t)G3 * H_SZ * 2);
  unsigned short* Wihp  = (unsigned short*)alloc((size_t)G3 * EO * 2);
  unsigned short* emb   = (unsigned short*)alloc((size_t)S_LEN * B_SZ * EH * 2);
  unsigned short* x     = (unsigned short*)alloc((size_t)S_LEN * B_SZ * EO * 2);
  unsigned short* hprep0 = (unsigned short*)alloc((size_t)B_SZ * H_SZ * 2);
  unsigned short* hprep1 = (unsigned short*)alloc((size_t)B_SZ * H_SZ * 2);
  unsigned short* hbfinal = (unsigned short*)alloc((size_t)B_SZ * H_SZ * 2);
  unsigned*       bar     = (unsigned*)alloc(1024);

  // fused weight converts (fp32 -> bf16): W2 | W_out -> one launch
  cvt2_bf16<<<dim3(1280), 256, 0, stream>>>(W2, W_out, W2b);

  // W_hh / W_ih -> MFMA-fragment-ordered bf16
  prep_whh<<<dim3(1536), 256, 0, stream>>>(W_hh, Wprep);
  prep_wih<<<dim3(768), 256, 0, stream>>>(W_ih, Wihp);

  // zero h0 (fragment-layout buffer read at s=0) and the 4 barrier counters
  hipMemsetAsync(hprep0, 0, (size_t)B_SZ * H_SZ * 2, stream);
  hipMemsetAsync(bar, 0, 1024, stream);

  // W1 transpose -> bf16
  transpose_w1_bf16<<<dim3(V_SZ / 64, EH / 64), 256, 0, stream>>>(W1, W1T);

  // embedding gather + b1 + threshold
  gather_emb<<<dim3(S_LEN * B_SZ / 4), 256, 0, stream>>>(ids, W1T, b1, emb);

  // x = thresh(emb @ W2^T + b2)
  gemm_bt<1, 1><<<dim3(EO / 128, S_LEN * B_SZ / 128), 256, 0, stream>>>(
      emb, W2b, b2, x, S_LEN * B_SZ, EO, EH);

  // persistent GRU recurrence (cooperative: all 256 blocks co-resident)
  // xW GEMM folded into the main MFMA block (xf prefetched one step ahead).
  {
    void* args[] = {(void*)&hprep0, (void*)&hprep1, (void*)&hbfinal,
                    (void*)&Wprep, (void*)&Wihp, (void*)&b_hh, (void*)&b_ih,
                    (void*)&x, (void*)&bar};
    hipLaunchCooperativeKernel((const void*)gru_persist, dim3(256), dim3(256),
                               args, 0, stream);
  }

  // out = h @ W_out^T + b_out
  gemm_bt<0, 0><<<dim3(O_SZ / 128, 1), 256, 0, stream>>>(
      hbfinal, Woutb, b_out, out, B_SZ, O_SZ, H_SZ);
}

// Round 8
// 591.601 us; speedup vs baseline: 1.2446x; 1.0497x over previous
//
#include <hip/hip_runtime.h>
#include <stdint.h>
#include <stddef.h>

// Problem constants
#define S_LEN 128
#define B_SZ  64
#define V_SZ  32000
#define EH    512
#define EO    512
#define H_SZ  1024
#define O_SZ  1024
#define G3    3072   // 3*H

typedef __attribute__((ext_vector_type(8))) short short8;
typedef __attribute__((ext_vector_type(4))) float floatx4;
typedef __attribute__((ext_vector_type(8))) unsigned short ushortx8;
typedef __attribute__((ext_vector_type(4))) unsigned uintx4;

__device__ __forceinline__ unsigned short f2bf(float f) {
  unsigned u = __builtin_bit_cast(unsigned, f);
  u += 0x7FFFu + ((u >> 16) & 1u);   // round-to-nearest-even
  return (unsigned short)(u >> 16);
}
__device__ __forceinline__ float bf2f(unsigned short h) {
  unsigned u = ((unsigned)h) << 16;
  return __builtin_bit_cast(float, u);
}

__device__ __forceinline__ void gld_lds16(const void* g, void* l) {
  __builtin_amdgcn_global_load_lds((const __attribute__((address_space(1))) void*)g,
                                   (__attribute__((address_space(3))) void*)l, 16, 0, 0);
}

// ------------------------------------------------- fused weight prep (ONE launch)
// seg A (256 blocks) : W2 fp32 -> flat bf16; block 0 also zeroes bar (1 KiB)
// seg B (1536 blocks): W_hh -> Wprep, MFMA-B-fragment order (96 chunks / cg)
// seg C (768 blocks) : W_ih -> Wihp, fragment order (48 chunks / cg)
// seg D (512 blocks) : W_out -> Woutp, fragment order (32 chunks / cg)
__global__ __launch_bounds__(256) void prep_all(const float* __restrict__ W2,
                                                const float* __restrict__ W_hh,
                                                const float* __restrict__ W_ih,
                                                const float* __restrict__ W_out,
                                                unsigned short* __restrict__ W2b,
                                                unsigned short* __restrict__ Wprep,
                                                unsigned short* __restrict__ Wihp,
                                                unsigned short* __restrict__ Woutp,
                                                unsigned* __restrict__ bar) {
  int b = blockIdx.x;
  int t = threadIdx.x;
  if (b < 256) {
    int i = b * 256 + t;                       // 65536 float4
    float4 v = ((const float4*)W2)[i];
    ushort4 o;
    o.x = f2bf(v.x); o.y = f2bf(v.y); o.z = f2bf(v.z); o.w = f2bf(v.w);
    ((ushort4*)W2b)[i] = o;
    if (b == 0) bar[t] = 0;                    // 256 dwords = 1 KiB
    return;
  }
  int lane, row, k;
  const float* src;
  ushortx8* dst;
  if (b < 256 + 1536) {
    int tid = (b - 256) * 256 + t;             // 393216
    lane = tid & 63;
    int c = tid >> 6;                          // 0..6143
    int cg = c / 96, r = c % 96, g = r >> 5, tt = r & 31;
    row = g * H_SZ + cg * 16 + (lane & 15);
    k   = tt * 32 + (lane >> 4) * 8;
    src = &W_hh[(size_t)row * H_SZ + k];
    dst = (ushortx8*)Wprep + tid;
  } else if (b < 256 + 1536 + 768) {
    int tid = (b - 1792) * 256 + t;            // 196608
    lane = tid & 63;
    int c = tid >> 6;                          // 0..3071
    int cg = c / 48, r = c % 48, g = r >> 4, kq = r & 15;
    row = g * H_SZ + cg * 16 + (lane & 15);
    k   = kq * 32 + (lane >> 4) * 8;
    src = &W_ih[(size_t)row * EO + k];
    dst = (ushortx8*)Wihp + tid;
  } else {
    int tid = (b - 2560) * 256 + t;            // 131072
    lane = tid & 63;
    int c = tid >> 6;                          // 0..2047
    int cg = c >> 5, kq = c & 31;
    row = cg * 16 + (lane & 15);
    k   = kq * 32 + (lane >> 4) * 8;
    src = &W_out[(size_t)row * H_SZ + k];
    dst = (ushortx8*)Woutp + tid;
  }
  float4 v0 = *(const float4*)src;
  float4 v1 = *(const float4*)(src + 4);
  ushortx8 o;
  o[0] = f2bf(v0.x); o[1] = f2bf(v0.y); o[2] = f2bf(v0.z); o[3] = f2bf(v0.w);
  o[4] = f2bf(v1.x); o[5] = f2bf(v1.y); o[6] = f2bf(v1.z); o[7] = f2bf(v1.w);
  *dst = o;
}

// ------------------------------------------------- W1 [EH][V] -> W1T bf16 [V][EH]
__global__ __launch_bounds__(256) void transpose_w1_bf16(const float* __restrict__ W1,
                                                         unsigned short* __restrict__ W1T) {
  __shared__ unsigned short tile[64][72];   // [v][e], padded
  int t = threadIdx.x;
  int v0 = blockIdx.x * 64;
  int e0 = blockIdx.y * 64;
  for (int i = 0; i < 4; ++i) {
    int e = (t >> 4) + i * 16;
    int v = (t & 15) * 4;
    float4 w = *(const float4*)&W1[(size_t)(e0 + e) * V_SZ + v0 + v];
    tile[v + 0][e] = f2bf(w.x);
    tile[v + 1][e] = f2bf(w.y);
    tile[v + 2][e] = f2bf(w.z);
    tile[v + 3][e] = f2bf(w.w);
  }
  __syncthreads();
  for (int i = 0; i < 2; ++i) {
    int v = (t >> 3) + i * 32;
    int e = (t & 7) * 8;
    ushortx8 o;
    for (int j = 0; j < 8; ++j) o[j] = tile[v][e + j];
    *(ushortx8*)&W1T[(size_t)(v0 + v) * EH + e0 + e] = o;
  }
}

// ------------------------------------------------- gather + b1 + threshold -> emb bf16
__global__ __launch_bounds__(256) void gather_emb(const int* __restrict__ ids,
                                                  const unsigned short* __restrict__ W1T,
                                                  const float* __restrict__ b1,
                                                  unsigned short* __restrict__ emb) {
  int t = threadIdx.x;
  int tok = blockIdx.x * 4 + (t >> 6);
  int lane = t & 63;
  int id = ids[tok];
  ushortx8 w = *(const ushortx8*)&W1T[(size_t)id * EH + lane * 8];
  float4 blo = *(const float4*)&b1[lane * 8];
  float4 bhi = *(const float4*)&b1[lane * 8 + 4];
  float bv[8] = {blo.x, blo.y, blo.z, blo.w, bhi.x, bhi.y, bhi.z, bhi.w};
  ushortx8 o;
  for (int j = 0; j < 8; ++j) {
    float x = bf2f(w[j]) + bv[j];
    x = (x > 1e-6f) ? x : 0.0f;
    o[j] = f2bf(x);
  }
  *(ushortx8*)&emb[(size_t)tok * EH + lane * 8] = o;
}

// ------------------------------------------------- MFMA GEMM, C = act(A @ B^T + bias)
// BK=64 + T2 XOR-swizzled LDS (16-B slots, slot ^= row&7); LDS dest of
// global_load_lds stays LINEAR, swizzle applied to the GLOBAL source slot.
template <int ACT, int OUT_BF16>
__global__ __launch_bounds__(256) void gemm_bt(const unsigned short* __restrict__ A,
                                               const unsigned short* __restrict__ B,
                                               const float* __restrict__ bias,
                                               void* __restrict__ Cout,
                                               int M, int N, int K) {
  __shared__ unsigned short lA[128 * 64];   // 16 KB, [row][slot^(row&7)] 16-B slots
  __shared__ unsigned short lB[128 * 64];   // 16 KB
  int t = threadIdx.x;
  int lane = t & 63;
  int wave = t >> 6;
  int bn = blockIdx.x, bm = blockIdx.y;
  int wm = (wave >> 1) * 64;
  int wn = (wave & 1) * 64;
  floatx4 acc[4][4] = {};

  int srow = t >> 3;                       // 0..31 within pass
  int sslot = (t & 7) ^ (srow & 7);        // logical (global) 16-B slot
  int scol = sslot * 8;                    // element offset within BK=64

  const unsigned short* aptr[4];
  const unsigned short* bptr[4];
#pragma unroll
  for (int p = 0; p < 4; ++p) {
    int gra = bm * 128 + p * 32 + srow;  if (gra >= M) gra = M - 1;
    aptr[p] = A + (size_t)gra * K + scol;
    bptr[p] = B + (size_t)(bn * 128 + p * 32 + srow) * K + scol;
  }

  for (int k0 = 0; k0 < K; k0 += 64) {
    __syncthreads();
#pragma unroll
    for (int p = 0; p < 4; ++p) {
      gld_lds16(aptr[p] + k0, &lA[p * 2048 + t * 8]);
      gld_lds16(bptr[p] + k0, &lB[p * 2048 + t * 8]);
    }
    __syncthreads();
#pragma unroll
    for (int kk = 0; kk < 2; ++kk) {
      short8 af[4], bfr[4];
#pragma unroll
      for (int i = 0; i < 4; ++i) {
        int row = wm + i * 16 + (lane & 15);
        int phys = (kk * 4 + (lane >> 4)) ^ (row & 7);
        af[i] = *(const short8*)&lA[row * 64 + phys * 8];
      }
#pragma unroll
      for (int j = 0; j < 4; ++j) {
        int row = wn + j * 16 + (lane & 15);
        int phys = (kk * 4 + (lane >> 4)) ^ (row & 7);
        bfr[j] = *(const short8*)&lB[row * 64 + phys * 8];
      }
#pragma unroll
      for (int i = 0; i < 4; ++i)
#pragma unroll
        for (int j = 0; j < 4; ++j)
          acc[i][j] = __builtin_amdgcn_mfma_f32_16x16x32_bf16(af[i], bfr[j], acc[i][j], 0, 0, 0);
    }
  }

  int rowq = (lane >> 4) * 4;
  for (int j = 0; j < 4; ++j) {
    int col = bn * 128 + wn + j * 16 + (lane & 15);
    float bv = bias[col];
    for (int i = 0; i < 4; ++i) {
      int row0 = bm * 128 + wm + i * 16 + rowq;
      for (int r = 0; r < 4; ++r) {
        int row = row0 + r;
        if (row < M) {
          float v = acc[i][j][r] + bv;
          if (ACT) v = (v > 1e-6f) ? v : 0.0f;
          if (OUT_BF16) ((unsigned short*)Cout)[(size_t)row * N + col] = f2bf(v);
          else          ((float*)Cout)[(size_t)row * N + col] = v;
        }
      }
    }
  }
}

// ------------------------------------------------- persistent GRU recurrence
// 256 blocks x 256 threads, cooperative. Block (bg,cg): batches [bg*16,+16),
// h-cols [cg*16,+16), all 3 gates; wave w = K-quarter [w*256,+256).
// Barrier: EXACT round-0 form (2.93 us/step): per-bg fetch_add counter +
// single-lane s_sleep(2) poll, empty wait window. Frozen (4 variants lost).
// xW fold (round-7, verified): xW MFMAs in the main MFMA block, xf prefetched
// one full step ahead, r/z accumulated into the W_hh accumulators.
//
// Round-8 additions:
//  - s==0: h-loads skipped (h0 == 0) -> hprep0 memset removed.
//  - barrier also runs at s = S_LEN-1; epilogue folds the final
//    out = h @ W_out^T + b_out GEMM: hbfinal exchanged via packed agent-scope
//    dwords, W_out fragment slice staged into lB (free after last step),
//    8 MFMA/wave over K=1024, lgh-reduce, fp32 store to d_out.
__global__ __launch_bounds__(256, 1) void gru_persist(const unsigned short* __restrict__ hprep0,
                                                      unsigned short* __restrict__ hprep1,
                                                      unsigned short* __restrict__ hbfinal,
                                                      const unsigned short* __restrict__ Wprep,
                                                      const unsigned short* __restrict__ Wihp,
                                                      const unsigned short* __restrict__ Woutp,
                                                      const float* __restrict__ b_hh,
                                                      const float* __restrict__ b_ih,
                                                      const float* __restrict__ b_out,
                                                      const unsigned short* __restrict__ x,
                                                      float* __restrict__ out,
                                                      unsigned* __restrict__ bar) {
  __shared__ unsigned short lB[96 * 512];    // 98304 B : W_hh slice; W_out slice in epilogue
  __shared__ unsigned short lWih[48 * 512];  // 49152 B : W_ih slice, fragment order
  __shared__ float lgh[3][4][256];           // 12288 B : per-wave K-partials (r,z merged)
  __shared__ float lgxn[4][256];             //  4096 B : per-wave xW n-gate partials
  // total 163840 B = full 160 KiB LDS
  int t = threadIdx.x;
  int lane = t & 63;
  int w = t >> 6;
  int bg = blockIdx.x >> 6;    // 0..3
  int cg = blockIdx.x & 63;    // 0..63

  // stage W_hh slice once (identity copy, 98 KB)
  const unsigned short* wsrc = Wprep + (size_t)cg * 96 * 512;
  for (int i = 0; i < 24; ++i) {
    int c = w * 24 + i;
    gld_lds16(wsrc + (size_t)c * 512 + lane * 8, &lB[c * 512 + lane * 8]);
  }
  // stage W_ih slice once (48 KB)
  const unsigned short* wxs = Wihp + (size_t)cg * 48 * 512;
  for (int i = 0; i < 12; ++i) {
    int c = w * 12 + i;
    gld_lds16(wxs + (size_t)c * 512 + lane * 8, &lWih[c * 512 + lane * 8]);
  }

  // per-thread update-element constants
  int b_loc = t >> 4;
  int j_loc = t & 15;
  int jcol = cg * 16 + j_loc;          // h column
  int bglob = bg * 16 + b_loc;         // batch
  float brz_r = b_hh[jcol] + b_ih[jcol];                    // merged r bias
  float brz_z = b_hh[H_SZ + jcol] + b_ih[H_SZ + jcol];      // merged z bias
  float bhn  = b_hh[2 * H_SZ + jcol];
  float bihn = b_ih[2 * H_SZ + jcol];
  // scatter-store position for h_new (A-fragment layout); lane pairs (jj even/odd)
  // pack 2 bf16 into one dword store.
  int tt2 = jcol >> 5;
  int q   = (jcol >> 3) & 3;
  int jj  = jcol & 7;
  int Ls  = b_loc | (q << 4);
  size_t hw_off32 = ((((size_t)(bg * 32 + tt2) * 64 + Ls) * 8) + (jj & ~1)) >> 1;

  const unsigned short* hbufs[2] = {hprep0, hprep1};
  unsigned* barp = bar + bg * 64;      // per-bg counter, 256 B apart
  float hmaster = 0.0f;                // fp32 master h for my (batch, col)

  // per-lane base for xW A-fragments (batch = lane&15, k0 = (lane>>4)*8);
  // wave w owns kq = 4w..4w+3  -> element offset kq*32
  const unsigned short* xbase =
      x + ((size_t)(bg * 16 + (lane & 15))) * EO + (lane >> 4) * 8 + (w * 4) * 32;

  __syncthreads();   // drains staging vmcnt (lB + lWih ready)

  // prologue: issue xf prefetch for s=0 (the loop's tied vmcnt(0) waits them)
  uintx4 xf[4];
#pragma unroll
  for (int i = 0; i < 4; ++i)
    asm volatile("global_load_dwordx4 %0, %1, off" : "=v"(xf[i]) : "v"(xbase + i * 32));

  for (int s = 0; s < S_LEN; ++s) {
    const unsigned short* hr = hbufs[s & 1];
    unsigned* hw32 = (unsigned*)hbufs[(s + 1) & 1];

    // A-fragments for my K-quarter. s==0: h0 == 0 -> zero fragments, no loads
    // (hprep0 is never read -> its memset is gone).
    uintx4 av[8];
    if (s == 0) {
#pragma unroll
      for (int i = 0; i < 8; ++i) av[i] = (uintx4){0u, 0u, 0u, 0u};
    } else {
#pragma unroll
      for (int i = 0; i < 8; ++i) {
        int tt = w * 8 + i;
        const void* ap = hr + ((size_t)(bg * 32 + tt) * 64 + lane) * 8;
        asm volatile("global_load_dwordx4 %0, %1, off sc1" : "=v"(av[i]) : "v"(ap));
      }
    }
    asm volatile("s_waitcnt vmcnt(0)"
                 : "+v"(av[0]), "+v"(av[1]), "+v"(av[2]), "+v"(av[3]),
                   "+v"(av[4]), "+v"(av[5]), "+v"(av[6]), "+v"(av[7]),
                   "+v"(xf[0]), "+v"(xf[1]), "+v"(xf[2]), "+v"(xf[3])
                 :: "memory");

    // main MFMA block: 24 W_hh MFMAs + 12 xW MFMAs (r,z merged into acc[0/1])
    floatx4 acc[3] = {};
    floatx4 accn = {};
#pragma unroll
    for (int i = 0; i < 8; ++i) {
      int tt = w * 8 + i;
      short8 a = __builtin_bit_cast(short8, av[i]);
#pragma unroll
      for (int g = 0; g < 3; ++g) {
        short8 bfr = *(const short8*)&lB[((g * 32 + tt) * 64 + lane) * 8];
        acc[g] = __builtin_amdgcn_mfma_f32_16x16x32_bf16(a, bfr, acc[g], 0, 0, 0);
      }
    }
#pragma unroll
    for (int i = 0; i < 4; ++i) {
      int kq = w * 4 + i;
      short8 a = __builtin_bit_cast(short8, xf[i]);
      short8 b0 = *(const short8*)&lWih[((0 * 16 + kq) * 64 + lane) * 8];
      short8 b1 = *(const short8*)&lWih[((1 * 16 + kq) * 64 + lane) * 8];
      short8 b2 = *(const short8*)&lWih[((2 * 16 + kq) * 64 + lane) * 8];
      acc[0] = __builtin_amdgcn_mfma_f32_16x16x32_bf16(a, b0, acc[0], 0, 0, 0);
      acc[1] = __builtin_amdgcn_mfma_f32_16x16x32_bf16(a, b1, acc[1], 0, 0, 0);
      accn   = __builtin_amdgcn_mfma_f32_16x16x32_bf16(a, b2, accn,   0, 0, 0);
    }

    // prefetch x A-fragments for step s+1 (full-step cover, 4 loads/thread)
    if (s + 1 < S_LEN) {
      const unsigned short* xrow = xbase + (size_t)(s + 1) * B_SZ * EO;
#pragma unroll
      for (int i = 0; i < 4; ++i)
        asm volatile("global_load_dwordx4 %0, %1, off" : "=v"(xf[i]) : "v"(xrow + i * 32));
    }

#pragma unroll
    for (int g = 0; g < 3; ++g)
#pragma unroll
      for (int r = 0; r < 4; ++r)
        lgh[g][w][((lane >> 4) * 4 + r) * 16 + (lane & 15)] = acc[g][r];
#pragma unroll
    for (int r = 0; r < 4; ++r)
      lgxn[w][((lane >> 4) * 4 + r) * 16 + (lane & 15)] = accn[r];
    __syncthreads();

    // gate update for my element (sum 4 K-partials; r,z already merged)
    float grs = lgh[0][0][t] + lgh[0][1][t] + lgh[0][2][t] + lgh[0][3][t] + brz_r;
    float gzs = lgh[1][0][t] + lgh[1][1][t] + lgh[1][2][t] + lgh[1][3][t] + brz_z;
    float ghn = lgh[2][0][t] + lgh[2][1][t] + lgh[2][2][t] + lgh[2][3][t] + bhn;
    float xnv = lgxn[0][t] + lgxn[1][t] + lgxn[2][t] + lgxn[3][t] + bihn;
    float rr = 1.0f / (1.0f + __expf(-grs));
    float zz = 1.0f / (1.0f + __expf(-gzs));
    float nn = tanhf(xnv + rr * ghn);
    float hnew = (1.0f - zz) * nn + zz * hmaster;
    hmaster = hnew;

    unsigned hb = (unsigned)f2bf(hnew);
    unsigned other = (unsigned)__shfl_xor((int)hb, 1);
    if ((jj & 1) == 0) {
      unsigned packed = hb | (other << 16);   // (jj, jj+1)
      __hip_atomic_store(hw32 + hw_off32, packed,
                         __ATOMIC_RELAXED, __HIP_MEMORY_SCOPE_AGENT);
      if (s == S_LEN - 1) {
        // row-major final h for the out-GEMM epilogue (same lane pairing:
        // jcol parity == jj parity)
        __hip_atomic_store((unsigned*)hbfinal + (((size_t)bglob * H_SZ + jcol) >> 1),
                           packed, __ATOMIC_RELAXED, __HIP_MEMORY_SCOPE_AGENT);
      }
    }

    // per-bg barrier EVERY step (incl. last: publishes hbfinal for epilogue)
    __syncthreads();   // waitcnt vmcnt(0) + barrier: h-stores at L3, xf loaded
    if (t == 0) {
      __hip_atomic_fetch_add(barp, 1u, __ATOMIC_RELAXED, __HIP_MEMORY_SCOPE_AGENT);
      unsigned target = 64u * (unsigned)(s + 1);
      while (__hip_atomic_load(barp, __ATOMIC_RELAXED, __HIP_MEMORY_SCOPE_AGENT) < target)
        __builtin_amdgcn_s_sleep(2);
    }
    __syncthreads();   // release
  }

  // ---- epilogue: out = h @ W_out^T + b_out (folded final GEMM) ----
  // lB is free (last lB reads were before the final barrier). Stage the
  // per-cg W_out fragment slice (32 chunks, 32 KB) and the h A-fragments
  // (row-major hbfinal, same pattern as the verified xW A-frags).
  {
    const unsigned short* wos = Woutp + (size_t)cg * 32 * 512;
#pragma unroll
    for (int i = 0; i < 8; ++i) {
      int c = w * 8 + i;
      gld_lds16(wos + (size_t)c * 512 + lane * 8, &lB[c * 512 + lane * 8]);
    }
    uintx4 hv[8];
#pragma unroll
    for (int i = 0; i < 8; ++i) {
      int kq = w * 8 + i;
      const void* hp = hbfinal + (size_t)(bg * 16 + (lane & 15)) * H_SZ +
                       kq * 32 + (lane >> 4) * 8;
      asm volatile("global_load_dwordx4 %0, %1, off sc1" : "=v"(hv[i]) : "v"(hp));
    }
    __syncthreads();   // drains staging + register loads
    asm volatile("s_waitcnt vmcnt(0)"
                 : "+v"(hv[0]), "+v"(hv[1]), "+v"(hv[2]), "+v"(hv[3]),
                   "+v"(hv[4]), "+v"(hv[5]), "+v"(hv[6]), "+v"(hv[7])
                 :: "memory");
    floatx4 acco = {};
#pragma unroll
    for (int i = 0; i < 8; ++i) {
      int kq = w * 8 + i;
      short8 a = __builtin_bit_cast(short8, hv[i]);
      short8 bfr = *(const short8*)&lB[kq * 512 + lane * 8];
      acco = __builtin_amdgcn_mfma_f32_16x16x32_bf16(a, bfr, acco, 0, 0, 0);
    }
#pragma unroll
    for (int r = 0; r < 4; ++r)
      lgh[0][w][((lane >> 4) * 4 + r) * 16 + (lane & 15)] = acco[r];
    __syncthreads();
    float o = lgh[0][0][t] + lgh[0][1][t] + lgh[0][2][t] + lgh[0][3][t] + b_out[jcol];
    out[(size_t)bglob * O_SZ + jcol] = o;
  }
}

// ----------------------------------------------------------------- launch
extern "C" void kernel_launch(void* const* d_in, const int* in_sizes, int n_in,
                              void* d_out, int out_size, void* d_ws, size_t ws_size,
                              hipStream_t stream) {
  const int*   ids   = (const int*)d_in[0];
  const float* W1    = (const float*)d_in[1];
  const float* b1    = (const float*)d_in[2];
  const float* W2    = (const float*)d_in[3];
  const float* b2    = (const float*)d_in[4];
  const float* W_ih  = (const float*)d_in[5];
  const float* b_ih  = (const float*)d_in[6];
  const float* W_hh  = (const float*)d_in[7];
  const float* b_hh  = (const float*)d_in[8];
  const float* W_out = (const float*)d_in[9];
  const float* b_out = (const float*)d_in[10];
  float* out = (float*)d_out;

  uint8_t* wsp = (uint8_t*)d_ws;
  auto alloc = [&](size_t bytes) {
    uint8_t* p = wsp;
    wsp += (bytes + 255) & ~(size_t)255;
    return p;
  };
  unsigned short* W1T   = (unsigned short*)alloc((size_t)V_SZ * EH * 2);
  unsigned short* W2b   = (unsigned short*)alloc((size_t)EO * EH * 2);
  unsigned short* Wprep = (unsigned short*)alloc((size_t)G3 * H_SZ * 2);
  unsigned short* Wihp  = (unsigned short*)alloc((size_t)G3 * EO * 2);
  unsigned short* Woutp = (unsigned short*)alloc((size_t)O_SZ * H_SZ * 2);
  unsigned short* emb   = (unsigned short*)alloc((size_t)S_LEN * B_SZ * EH * 2);
  unsigned short* x     = (unsigned short*)alloc((size_t)S_LEN * B_SZ * EO * 2);
  unsigned short* hprep0 = (unsigned short*)alloc((size_t)B_SZ * H_SZ * 2);
  unsigned short* hprep1 = (unsigned short*)alloc((size_t)B_SZ * H_SZ * 2);
  unsigned short* hbfinal = (unsigned short*)alloc((size_t)B_SZ * H_SZ * 2);
  unsigned*       bar     = (unsigned*)alloc(1024);

  // ALL weight prep in one launch (W2 cvt, W_hh/W_ih/W_out fragment prep,
  // bar zeroing). hprep0 memset removed (gru's s==0 uses zero fragments).
  prep_all<<<dim3(3072), 256, 0, stream>>>(W2, W_hh, W_ih, W_out,
                                           W2b, Wprep, Wihp, Woutp, bar);

  // W1 transpose -> bf16
  transpose_w1_bf16<<<dim3(V_SZ / 64, EH / 64), 256, 0, stream>>>(W1, W1T);

  // embedding gather + b1 + threshold
  gather_emb<<<dim3(S_LEN * B_SZ / 4), 256, 0, stream>>>(ids, W1T, b1, emb);

  // x = thresh(emb @ W2^T + b2)
  gemm_bt<1, 1><<<dim3(EO / 128, S_LEN * B_SZ / 128), 256, 0, stream>>>(
      emb, W2b, b2, x, S_LEN * B_SZ, EO, EH);

  // persistent GRU recurrence (cooperative: all 256 blocks co-resident)
  // xW GEMM folded into the main MFMA block; out-GEMM folded into epilogue.
  {
    void* args[] = {(void*)&hprep0, (void*)&hprep1, (void*)&hbfinal,
                    (void*)&Wprep, (void*)&Wihp, (void*)&Woutp,
                    (void*)&b_hh, (void*)&b_ih, (void*)&b_out,
                    (void*)&x, (void*)&out, (void*)&bar};
    hipLaunchCooperativeKernel((const void*)gru_persist, dim3(256), dim3(256),
                               args, 0, stream);
  }
}